// Round 4
// baseline (512.256 us; speedup 1.0000x reference)
//
#include <hip/hip_runtime.h>
#include <hip/hip_bf16.h>

using bf16 = __hip_bfloat16;

#define F 64
#define HG 128
#define HL 128
#define AVG_LOG_INV 0.45511961331341866f  // 1/log(9)

__device__ __forceinline__ float b2f(bf16 v) { return __bfloat162float(v); }
__device__ __forceinline__ bf16 f2b(float v) { return __float2bfloat16(v); }

__device__ __forceinline__ unsigned packbf2(float x, float y) {
    bf16 a = f2b(x), b = f2b(y);
    unsigned short ua = *(unsigned short*)&a, ub = *(unsigned short*)&b;
    return ((unsigned)ub << 16) | (unsigned)ua;
}

// fused: zero cnt/gfeat/gcnt + compute uc[128] in the last block
// u[f] = sum_k W_edge[k]*Wpre3[k][f];  c[f] = b_pre[f] + sum_k b_edge[k]*Wpre3[k][f]
__global__ void k_init(int* __restrict__ cnt, float* __restrict__ gfeat,
                       int* __restrict__ gcnt, int N, int GF, int G,
                       const float* __restrict__ W_edge, const float* __restrict__ b_edge,
                       const float* __restrict__ W_pre, const float* __restrict__ b_pre,
                       float* __restrict__ uc) {
    if (blockIdx.x == gridDim.x - 1) {
        int f = threadIdx.x;
        if (f < 64) {
            float u = 0.f, c = b_pre[f];
            for (int k = 0; k < 64; k++) {
                float w3 = W_pre[(128 + k) * 64 + f];
                u += W_edge[k] * w3;
                c += b_edge[k] * w3;
            }
            uc[f] = u; uc[64 + f] = c;
        } else if (f - 64 < G) {
            gcnt[f - 64] = 0;
        }
        return;
    }
    int i = blockIdx.x * 256 + threadIdx.x;
    if (i < N) cnt[i] = 0;
    if (i < GF) gfeat[i] = 0.f;
}

// fused: AB staging (blocks < AB_BLOCKS) + degree histogram (remaining blocks)
// AB[n][0:64] = x[n]@Wpre1, AB[n][64:128] = x[n]@Wpre2  (bf16, internal)
__global__ void k_abhist(const float* __restrict__ x, const float* __restrict__ W_pre,
                         bf16* __restrict__ AB, int N,
                         const int* __restrict__ ei, int* __restrict__ cnt, int E,
                         int AB_BLOCKS) {
    if ((int)blockIdx.x >= AB_BLOCKS) {
        int nhb = gridDim.x - AB_BLOCKS;
        int stride = nhb * 256;
        for (int e = (blockIdx.x - AB_BLOCKS) * 256 + threadIdx.x; e < E; e += stride)
            atomicAdd(&cnt[ei[E + e]], 1);
        return;
    }
    __shared__ float w1[64 * 64], w2[64 * 64];
    for (int i = threadIdx.x; i < 4096; i += blockDim.x) {
        w1[i] = W_pre[i];
        w2[i] = W_pre[4096 + i];
    }
    __syncthreads();
    int lane = threadIdx.x & 63;
    int wid = (blockIdx.x * 256 + threadIdx.x) >> 6;
    int nw = (AB_BLOCKS * 256) >> 6;
    for (int n = wid; n < N; n += nw) {
        float xv = x[(size_t)n * 64 + lane];
        float a0 = 0.f, a1 = 0.f;
        #pragma unroll
        for (int k = 0; k < 64; k++) {
            float xs = __shfl(xv, k);
            a0 += xs * w1[k * 64 + lane];
            a1 += xs * w2[k * 64 + lane];
        }
        AB[(size_t)n * 128 + lane] = f2b(a0);
        AB[(size_t)n * 128 + 64 + lane] = f2b(a1);
    }
}

__global__ void k_scan1(const int* __restrict__ cnt, int* __restrict__ csum, int N) {
    __shared__ int s[256];
    int i = blockIdx.x * 256 + threadIdx.x;
    s[threadIdx.x] = (i < N) ? cnt[i] : 0;
    __syncthreads();
    for (int st = 128; st > 0; st >>= 1) {
        if (threadIdx.x < st) s[threadIdx.x] += s[threadIdx.x + st];
        __syncthreads();
    }
    if (threadIdx.x == 0) csum[blockIdx.x] = s[0];
}

// exclusive scan of csum[0..NCH), NCH <= 256
__global__ void k_scan2(int* csum, int NCH) {
    __shared__ int s[256];
    int t = threadIdx.x;
    int v = (t < NCH) ? csum[t] : 0;
    s[t] = v;
    __syncthreads();
    for (int st = 1; st < 256; st <<= 1) {
        int a = (t >= st) ? s[t - st] : 0;
        __syncthreads();
        s[t] += a;
        __syncthreads();
    }
    if (t < NCH) csum[t] = s[t] - v;
}

__global__ void k_scan3(const int* __restrict__ cnt, const int* __restrict__ csum,
                        int* __restrict__ offs, int* __restrict__ cursor, int N, int E) {
    __shared__ int s[256];
    int t = threadIdx.x;
    int i = blockIdx.x * 256 + t;
    int v = (i < N) ? cnt[i] : 0;
    s[t] = v;
    __syncthreads();
    for (int st = 1; st < 256; st <<= 1) {
        int a = (t >= st) ? s[t - st] : 0;
        __syncthreads();
        s[t] += a;
        __syncthreads();
    }
    int excl = s[t] - v + csum[blockIdx.x];
    if (i < N) { offs[i] = excl; cursor[i] = excl; }
    if (i == 0) offs[N] = E;
}

// packed edge record: (src node, edge_attr bits) — one 8B store per edge
__global__ void k_scatter(const int* __restrict__ ei, const float* __restrict__ ea,
                          int* __restrict__ cursor, int2* __restrict__ srec, int E) {
    int e = blockIdx.x * blockDim.x + threadIdx.x;
    if (e >= E) return;
    int d = ei[E + e];
    int p = atomicAdd(&cursor[d], 1);
    srec[p] = make_int2(ei[e], __float_as_int(ea[e]));
}

// one wave per node; lanes split 32/32 over two edges per iteration,
// each lane handles a bf16x2 feature pair; edge records batched via lane loads + shfl
__global__ void k_edge(const bf16* __restrict__ AB, const int* __restrict__ offs,
                       const int2* __restrict__ srec, const float* __restrict__ uc,
                       bf16* __restrict__ agg, float* __restrict__ ampv, int N) {
    int lane = threadIdx.x & 63;
    int n = (blockIdx.x * blockDim.x + threadIdx.x) >> 6;
    if (n >= N) return;
    int lo = offs[n], hi = offs[n + 1];
    int cnt = hi - lo;
    int half = lane & 31;   // feature-pair index (features 2*half, 2*half+1)
    int hi32 = lane >> 5;   // which edge of the pair

    unsigned apack = *(const unsigned*)(AB + (size_t)n * 128 + 2 * half);
    float ax = __uint_as_float(apack << 16);
    float ay = __uint_as_float(apack & 0xffff0000u);
    float2 u2 = *(const float2*)(uc + 2 * half);
    float2 c2 = *(const float2*)(uc + 64 + 2 * half);
    float acx = ax + c2.x, acy = ay + c2.y;

    float sx = 0.f, sy = 0.f, qx = 0.f, qy = 0.f;
    float mnx = 3.4e38f, mny = 3.4e38f, mxx = -3.4e38f, mxy = -3.4e38f;

    for (int base = lo; base < hi; base += 64) {
        int nb = hi - base; if (nb > 64) nb = 64;
        int2 rec = make_int2(0, 0);
        if (lane < nb) rec = srec[base + lane];
        int vsn = rec.x;
        float vea = __int_as_float(rec.y);
        int full = nb & ~1;
        for (int i = 0; i < full; i += 2) {
            int   sn = __shfl(vsn, i + hi32);
            float eav = __shfl(vea, i + hi32);
            unsigned bp = *(const unsigned*)(AB + (size_t)sn * 128 + 64 + 2 * half);
            float bx = __uint_as_float(bp << 16);
            float by = __uint_as_float(bp & 0xffff0000u);
            float m0 = fmaf(eav, u2.x, acx) + bx;
            float m1 = fmaf(eav, u2.y, acy) + by;
            sx += m0; qx = fmaf(m0, m0, qx);
            sy += m1; qy = fmaf(m1, m1, qy);
            mnx = fminf(mnx, m0); mxx = fmaxf(mxx, m0);
            mny = fminf(mny, m1); mxy = fmaxf(mxy, m1);
        }
        if (nb & 1) {
            int   sn = __shfl(vsn, full);
            float eav = __shfl(vea, full);
            unsigned bp = *(const unsigned*)(AB + (size_t)sn * 128 + 64 + 2 * half);
            float bx = __uint_as_float(bp << 16);
            float by = __uint_as_float(bp & 0xffff0000u);
            float m0 = fmaf(eav, u2.x, acx) + bx;
            float m1 = fmaf(eav, u2.y, acy) + by;
            if (hi32 == 0) {
                sx += m0; qx = fmaf(m0, m0, qx);
                sy += m1; qy = fmaf(m1, m1, qy);
                mnx = fminf(mnx, m0); mxx = fmaxf(mxx, m0);
                mny = fminf(mny, m1); mxy = fmaxf(mxy, m1);
            }
        }
    }
    // merge the two edge-halves (lanes l and l+32 hold the same feature pair)
    sx += __shfl_xor(sx, 32); sy += __shfl_xor(sy, 32);
    qx += __shfl_xor(qx, 32); qy += __shfl_xor(qy, 32);
    mnx = fminf(mnx, __shfl_xor(mnx, 32)); mny = fminf(mny, __shfl_xor(mny, 32));
    mxx = fmaxf(mxx, __shfl_xor(mxx, 32)); mxy = fmaxf(mxy, __shfl_xor(mxy, 32));

    float c1 = (cnt > 0) ? (float)cnt : 1.f;
    float inv = 1.f / c1;
    float mex = sx * inv, mey = sy * inv;
    float vx = qx * inv - mex * mex; if (vx < 0.f) vx = 0.f;
    float vy = qy * inv - mey * mey; if (vy < 0.f) vy = 0.f;
    float sdx = sqrtf(vx + 1e-5f), sdy = sqrtf(vy + 1e-5f);
    if (cnt == 0) { mnx = mny = mxx = mxy = 0.f; }

    size_t b = (size_t)n * 256 + 2 * half;
    if (hi32 == 0) {
        *(unsigned*)(agg + b)       = packbf2(mex, mey);
        *(unsigned*)(agg + b + 64)  = packbf2(mnx, mny);
    } else {
        *(unsigned*)(agg + b + 128) = packbf2(mxx, mxy);
        *(unsigned*)(agg + b + 192) = packbf2(sdx, sdy);
    }
    if (lane == 0) ampv[n] = logf(c1 + 1.f) * AVG_LOG_INV;
}

// chunked per-graph SUM of 832-dim feature vector [x | agg | agg*amp | agg/amp]
__global__ void k_greduce2(const float* __restrict__ x, const bf16* __restrict__ agg,
                           const float* __restrict__ ampv, const int* __restrict__ batch,
                           float* __restrict__ gfeat, int* __restrict__ gcnt,
                           int N, int chunk) {
    int t = threadIdx.x;  // 256
    int lo = blockIdx.x * chunk;
    int hi = lo + chunk; if (hi > N) hi = N;
    if (lo >= hi) return;
    int curg = batch[lo];
    float s1 = 0.f, s2 = 0.f, s3 = 0.f, sx = 0.f;
    int cnt = 0;
    for (int n = lo; n < hi; n++) {
        int g = batch[n];
        if (g != curg) {
            float* gf = gfeat + (size_t)curg * 832;
            atomicAdd(&gf[64 + t], s1);
            atomicAdd(&gf[320 + t], s2);
            atomicAdd(&gf[576 + t], s3);
            if (t < 64) atomicAdd(&gf[t], sx);
            if (t == 0) atomicAdd(&gcnt[curg], cnt);
            s1 = s2 = s3 = sx = 0.f; cnt = 0; curg = g;
        }
        float amp = ampv[n];
        float av = b2f(agg[(size_t)n * 256 + t]);
        s1 += av; s2 += av * amp; s3 += av / amp;
        if (t < 64) sx += x[(size_t)n * 64 + t];
        cnt++;
    }
    float* gf = gfeat + (size_t)curg * 832;
    atomicAdd(&gf[64 + t], s1);
    atomicAdd(&gf[320 + t], s2);
    atomicAdd(&gf[576 + t], s3);
    if (t < 64) atomicAdd(&gf[t], sx);
    if (t == 0) atomicAdd(&gcnt[curg], cnt);
}

// Zin[g] = ((gfeat[g]/cnt) @ W_post + b_post) @ W_lin + b_lin ; zero if empty graph
__global__ void k_post1(const float* __restrict__ gfeat, const int* __restrict__ gcnt,
                        const float* __restrict__ W_post, const float* __restrict__ b_post,
                        const float* __restrict__ W_lin, const float* __restrict__ b_lin,
                        float* __restrict__ Zin) {
    int g = blockIdx.x, j = threadIdx.x;  // 128
    __shared__ float feat[832];
    __shared__ float z1[128];
    int cg = gcnt[g];
    float r = 1.f / ((cg > 0) ? (float)cg : 1.f);
    for (int i = j; i < 832; i += 128) feat[i] = gfeat[(size_t)g * 832 + i] * r;
    __syncthreads();
    float acc = b_post[j];
    for (int k = 0; k < 832; k++) acc += feat[k] * W_post[k * 128 + j];
    z1[j] = acc;
    __syncthreads();
    float a2 = b_lin[j];
    for (int k = 0; k < 128; k++) a2 += z1[k] * W_lin[k * 128 + j];
    if (cg == 0) a2 = 0.f;
    Zin[g * 128 + j] = a2;
}

// fused tail: bn1+relu, @W2+bn2+relu, @Wr1+bn+relu, @Wr2+bn+res+relu, @W_out
// single block, 256 threads; 64x128 matrices live in LDS
__global__ void k_tail(const float* __restrict__ Zin,
                       const float* g1, const float* be1,
                       const float* __restrict__ W2, const float* b2,
                       const float* g2, const float* be2,
                       const float* __restrict__ Wr1, const float* br1,
                       const float* gr1, const float* ber1,
                       const float* __restrict__ Wr2, const float* br2,
                       const float* gr2, const float* ber2,
                       const float* __restrict__ W_out, const float* b_out,
                       float* __restrict__ out) {
    __shared__ float A[64 * 129], B[64 * 129], C[64 * 129];
    int t = threadIdx.x;  // 256

    for (int i = t; i < 8192; i += 256) A[(i >> 7) * 129 + (i & 127)] = Zin[i];
    __syncthreads();

    // BN1 + relu in place on A
    if (t < 128) {
        int c = t;
        float mu = 0.f;
        for (int r = 0; r < 64; r++) mu += A[r * 129 + c];
        mu *= (1.f / 64.f);
        float var = 0.f;
        for (int r = 0; r < 64; r++) { float d = A[r * 129 + c] - mu; var += d * d; }
        var *= (1.f / 64.f);
        float sc = rsqrtf(var + 1e-5f) * g1[c], sh = be1[c];
        for (int r = 0; r < 64; r++) {
            float v = (A[r * 129 + c] - mu) * sc + sh;
            A[r * 129 + c] = v > 0.f ? v : 0.f;
        }
    }
    __syncthreads();

    // B = A @ W2 + b2
    {
        int c = t & 127, r0 = (t >> 7) * 32;
        for (int r = r0; r < r0 + 32; r++) {
            float acc = b2[c];
            for (int k = 0; k < 128; k++) acc += A[r * 129 + k] * W2[k * 128 + c];
            B[r * 129 + c] = acc;
        }
    }
    __syncthreads();
    // BN2 + relu on B   (B = residual afterwards)
    if (t < 128) {
        int c = t;
        float mu = 0.f;
        for (int r = 0; r < 64; r++) mu += B[r * 129 + c];
        mu *= (1.f / 64.f);
        float var = 0.f;
        for (int r = 0; r < 64; r++) { float d = B[r * 129 + c] - mu; var += d * d; }
        var *= (1.f / 64.f);
        float sc = rsqrtf(var + 1e-5f) * g2[c], sh = be2[c];
        for (int r = 0; r < 64; r++) {
            float v = (B[r * 129 + c] - mu) * sc + sh;
            B[r * 129 + c] = v > 0.f ? v : 0.f;
        }
    }
    __syncthreads();

    // C = B @ Wr1 + br1 ; BN(gr1,ber1) + relu
    {
        int c = t & 127, r0 = (t >> 7) * 32;
        for (int r = r0; r < r0 + 32; r++) {
            float acc = br1[c];
            for (int k = 0; k < 128; k++) acc += B[r * 129 + k] * Wr1[k * 128 + c];
            C[r * 129 + c] = acc;
        }
    }
    __syncthreads();
    if (t < 128) {
        int c = t;
        float mu = 0.f;
        for (int r = 0; r < 64; r++) mu += C[r * 129 + c];
        mu *= (1.f / 64.f);
        float var = 0.f;
        for (int r = 0; r < 64; r++) { float d = C[r * 129 + c] - mu; var += d * d; }
        var *= (1.f / 64.f);
        float sc = rsqrtf(var + 1e-5f) * gr1[c], sh = ber1[c];
        for (int r = 0; r < 64; r++) {
            float v = (C[r * 129 + c] - mu) * sc + sh;
            C[r * 129 + c] = v > 0.f ? v : 0.f;
        }
    }
    __syncthreads();

    // A = C @ Wr2 + br2 ; BN(gr2,ber2) + B (residual) + relu
    {
        int c = t & 127, r0 = (t >> 7) * 32;
        for (int r = r0; r < r0 + 32; r++) {
            float acc = br2[c];
            for (int k = 0; k < 128; k++) acc += C[r * 129 + k] * Wr2[k * 128 + c];
            A[r * 129 + c] = acc;
        }
    }
    __syncthreads();
    if (t < 128) {
        int c = t;
        float mu = 0.f;
        for (int r = 0; r < 64; r++) mu += A[r * 129 + c];
        mu *= (1.f / 64.f);
        float var = 0.f;
        for (int r = 0; r < 64; r++) { float d = A[r * 129 + c] - mu; var += d * d; }
        var *= (1.f / 64.f);
        float sc = rsqrtf(var + 1e-5f) * gr2[c], sh = ber2[c];
        for (int r = 0; r < 64; r++) {
            float v = (A[r * 129 + c] - mu) * sc + sh + B[r * 129 + c];
            A[r * 129 + c] = v > 0.f ? v : 0.f;
        }
    }
    __syncthreads();

    if (t < 64) {
        float acc = b_out[0];
        for (int j = 0; j < 128; j++) acc += A[t * 129 + j] * W_out[j];
        out[t] = acc;
    }
}

extern "C" void kernel_launch(void* const* d_in, const int* in_sizes, int n_in,
                              void* d_out, int out_size, void* d_ws, size_t ws_size,
                              hipStream_t stream) {
    const float* x      = (const float*)d_in[0];
    const int*   ei     = (const int*)d_in[1];
    const float* ea     = (const float*)d_in[2];
    const int*   batch  = (const int*)d_in[3];
    const float* W_edge = (const float*)d_in[4];
    const float* b_edge = (const float*)d_in[5];
    const float* W_pre  = (const float*)d_in[6];
    const float* b_pre  = (const float*)d_in[7];
    const float* W_post = (const float*)d_in[8];
    const float* b_post = (const float*)d_in[9];
    const float* W_lin  = (const float*)d_in[10];
    const float* b_lin  = (const float*)d_in[11];
    const float* g1     = (const float*)d_in[12];
    const float* be1    = (const float*)d_in[13];
    const float* W2     = (const float*)d_in[14];
    const float* b2     = (const float*)d_in[15];
    const float* g2     = (const float*)d_in[16];
    const float* be2    = (const float*)d_in[17];
    const float* Wr1    = (const float*)d_in[18];
    const float* br1    = (const float*)d_in[19];
    const float* gr1    = (const float*)d_in[20];
    const float* ber1   = (const float*)d_in[21];
    const float* Wr2    = (const float*)d_in[22];
    const float* br2    = (const float*)d_in[23];
    const float* gr2    = (const float*)d_in[24];
    const float* ber2   = (const float*)d_in[25];
    const float* W_out  = (const float*)d_in[26];
    const float* b_out  = (const float*)d_in[27];
    float* out = (float*)d_out;

    const int N = in_sizes[0] / F;      // 50000
    const int E = in_sizes[1] / 2;      // 800000
    const int G = out_size;             // 64

    char* p = (char*)d_ws;
    auto alloc = [&](size_t nbytes) { void* r = p; p += (nbytes + 255) & ~(size_t)255; return r; };
    bf16*  AB     = (bf16*)alloc((size_t)N * 128 * sizeof(bf16));
    bf16*  agg    = (bf16*)alloc((size_t)N * 256 * sizeof(bf16));
    float* ampv   = (float*)alloc((size_t)N * sizeof(float));
    int*   cnt    = (int*)alloc((size_t)N * sizeof(int));
    int*   offs   = (int*)alloc((size_t)(N + 1) * sizeof(int));
    int*   cursor = (int*)alloc((size_t)N * sizeof(int));
    int*   csum   = (int*)alloc(512 * sizeof(int));
    int2*  srec   = (int2*)alloc((size_t)E * sizeof(int2));
    float* uc     = (float*)alloc(128 * sizeof(float));
    float* gfeat  = (float*)alloc((size_t)G * 832 * sizeof(float));
    int*   gcnt   = (int*)alloc((size_t)G * sizeof(int));
    float* Zin    = (float*)alloc(64 * 128 * sizeof(float));

    const int NCH = (N + 255) / 256;    // 196 (must be <= 256)
    const int EB = (E + 255) / 256;
    const int AB_BLOCKS = 1024, HIST_BLOCKS = 512;
    const int GRB = 512;
    const int GRCH = (N + GRB - 1) / GRB;

    k_init<<<NCH + 1, 256, 0, stream>>>(cnt, gfeat, gcnt, N, G * 832, G,
                                        W_edge, b_edge, W_pre, b_pre, uc);
    k_abhist<<<AB_BLOCKS + HIST_BLOCKS, 256, 0, stream>>>(x, W_pre, AB, N, ei, cnt, E, AB_BLOCKS);
    k_scan1<<<NCH, 256, 0, stream>>>(cnt, csum, N);
    k_scan2<<<1, 256, 0, stream>>>(csum, NCH);
    k_scan3<<<NCH, 256, 0, stream>>>(cnt, csum, offs, cursor, N, E);
    k_scatter<<<EB, 256, 0, stream>>>(ei, ea, cursor, srec, E);
    k_edge<<<(N * 64 + 255) / 256, 256, 0, stream>>>(AB, offs, srec, uc, agg, ampv, N);
    k_greduce2<<<GRB, 256, 0, stream>>>(x, agg, ampv, batch, gfeat, gcnt, N, GRCH);
    k_post1<<<G, 128, 0, stream>>>(gfeat, gcnt, W_post, b_post, W_lin, b_lin, Zin);
    k_tail<<<1, 256, 0, stream>>>(Zin, g1, be1, W2, b2, g2, be2,
                                  Wr1, br1, gr1, ber1, Wr2, br2, gr2, ber2,
                                  W_out, b_out, out);
}

// Round 5
// 390.543 us; speedup vs baseline: 1.3117x; 1.3117x over previous
//
#include <hip/hip_runtime.h>
#include <hip/hip_bf16.h>

using bf16 = __hip_bfloat16;

#define F 64
#define HG 128
#define HL 128
#define AVG_LOG_INV 0.45511961331341866f  // 1/log(9)

__device__ __forceinline__ float b2f(bf16 v) { return __bfloat162float(v); }
__device__ __forceinline__ bf16 f2b(float v) { return __float2bfloat16(v); }

__device__ __forceinline__ unsigned packbf2(float x, float y) {
    bf16 a = f2b(x), b = f2b(y);
    unsigned short ua = *(unsigned short*)&a, ub = *(unsigned short*)&b;
    return ((unsigned)ub << 16) | (unsigned)ua;
}

__device__ __forceinline__ float wave_sum(float v) {
    #pragma unroll
    for (int m = 32; m > 0; m >>= 1) v += __shfl_xor(v, m);
    return v;
}

// fused: zero cnt/gfeat/gcnt + compute uc[128] in the last block
__global__ void k_init(int* __restrict__ cnt, float* __restrict__ gfeat,
                       int* __restrict__ gcnt, int N, int GF, int G,
                       const float* __restrict__ W_edge, const float* __restrict__ b_edge,
                       const float* __restrict__ W_pre, const float* __restrict__ b_pre,
                       float* __restrict__ uc) {
    if (blockIdx.x == gridDim.x - 1) {
        int f = threadIdx.x;
        if (f < 64) {
            float u = 0.f, c = b_pre[f];
            for (int k = 0; k < 64; k++) {
                float w3 = W_pre[(128 + k) * 64 + f];
                u += W_edge[k] * w3;
                c += b_edge[k] * w3;
            }
            uc[f] = u; uc[64 + f] = c;
        } else if (f - 64 < G) {
            gcnt[f - 64] = 0;
        }
        return;
    }
    int i = blockIdx.x * 256 + threadIdx.x;
    if (i < N) cnt[i] = 0;
    if (i < GF) gfeat[i] = 0.f;
}

// fused: AB staging (blocks < AB_BLOCKS) + degree histogram (remaining blocks)
__global__ void k_abhist(const float* __restrict__ x, const float* __restrict__ W_pre,
                         bf16* __restrict__ AB, int N,
                         const int* __restrict__ ei, int* __restrict__ cnt, int E,
                         int AB_BLOCKS) {
    if ((int)blockIdx.x >= AB_BLOCKS) {
        int nhb = gridDim.x - AB_BLOCKS;
        int stride = nhb * 256;
        for (int e = (blockIdx.x - AB_BLOCKS) * 256 + threadIdx.x; e < E; e += stride)
            atomicAdd(&cnt[ei[E + e]], 1);
        return;
    }
    __shared__ float w1[64 * 64], w2[64 * 64];
    for (int i = threadIdx.x; i < 4096; i += blockDim.x) {
        w1[i] = W_pre[i];
        w2[i] = W_pre[4096 + i];
    }
    __syncthreads();
    int lane = threadIdx.x & 63;
    int wid = (blockIdx.x * 256 + threadIdx.x) >> 6;
    int nw = (AB_BLOCKS * 256) >> 6;
    for (int n = wid; n < N; n += nw) {
        float xv = x[(size_t)n * 64 + lane];
        float a0 = 0.f, a1 = 0.f;
        #pragma unroll
        for (int k = 0; k < 64; k++) {
            float xs = __shfl(xv, k);
            a0 += xs * w1[k * 64 + lane];
            a1 += xs * w2[k * 64 + lane];
        }
        AB[(size_t)n * 128 + lane] = f2b(a0);
        AB[(size_t)n * 128 + 64 + lane] = f2b(a1);
    }
}

__global__ void k_scan1(const int* __restrict__ cnt, int* __restrict__ csum, int N) {
    __shared__ int s[256];
    int i = blockIdx.x * 256 + threadIdx.x;
    s[threadIdx.x] = (i < N) ? cnt[i] : 0;
    __syncthreads();
    for (int st = 128; st > 0; st >>= 1) {
        if (threadIdx.x < st) s[threadIdx.x] += s[threadIdx.x + st];
        __syncthreads();
    }
    if (threadIdx.x == 0) csum[blockIdx.x] = s[0];
}

// exclusive scan of csum[0..NCH), NCH <= 256
__global__ void k_scan2(int* csum, int NCH) {
    __shared__ int s[256];
    int t = threadIdx.x;
    int v = (t < NCH) ? csum[t] : 0;
    s[t] = v;
    __syncthreads();
    for (int st = 1; st < 256; st <<= 1) {
        int a = (t >= st) ? s[t - st] : 0;
        __syncthreads();
        s[t] += a;
        __syncthreads();
    }
    if (t < NCH) csum[t] = s[t] - v;
}

__global__ void k_scan3(const int* __restrict__ cnt, const int* __restrict__ csum,
                        int* __restrict__ offs, int* __restrict__ cursor, int N, int E) {
    __shared__ int s[256];
    int t = threadIdx.x;
    int i = blockIdx.x * 256 + t;
    int v = (i < N) ? cnt[i] : 0;
    s[t] = v;
    __syncthreads();
    for (int st = 1; st < 256; st <<= 1) {
        int a = (t >= st) ? s[t - st] : 0;
        __syncthreads();
        s[t] += a;
        __syncthreads();
    }
    int excl = s[t] - v + csum[blockIdx.x];
    if (i < N) { offs[i] = excl; cursor[i] = excl; }
    if (i == 0) offs[N] = E;
}

// packed edge record: (src node, edge_attr bits) — one 8B store per edge
__global__ void k_scatter(const int* __restrict__ ei, const float* __restrict__ ea,
                          int* __restrict__ cursor, int2* __restrict__ srec, int E) {
    int e = blockIdx.x * blockDim.x + threadIdx.x;
    if (e >= E) return;
    int d = ei[E + e];
    int p = atomicAdd(&cursor[d], 1);
    srec[p] = make_int2(ei[e], __float_as_int(ea[e]));
}

// one wave per node; lanes split 32/32 over two edges per iteration,
// each lane handles a bf16x2 feature pair; edge records batched via lane loads + shfl
__global__ void k_edge(const bf16* __restrict__ AB, const int* __restrict__ offs,
                       const int2* __restrict__ srec, const float* __restrict__ uc,
                       bf16* __restrict__ agg, float* __restrict__ ampv, int N) {
    int lane = threadIdx.x & 63;
    int n = (blockIdx.x * blockDim.x + threadIdx.x) >> 6;
    if (n >= N) return;
    int lo = offs[n], hi = offs[n + 1];
    int cnt = hi - lo;
    int half = lane & 31;   // feature-pair index (features 2*half, 2*half+1)
    int hi32 = lane >> 5;   // which edge of the pair

    unsigned apack = *(const unsigned*)(AB + (size_t)n * 128 + 2 * half);
    float ax = __uint_as_float(apack << 16);
    float ay = __uint_as_float(apack & 0xffff0000u);
    float2 u2 = *(const float2*)(uc + 2 * half);
    float2 c2 = *(const float2*)(uc + 64 + 2 * half);
    float acx = ax + c2.x, acy = ay + c2.y;

    float sx = 0.f, sy = 0.f, qx = 0.f, qy = 0.f;
    float mnx = 3.4e38f, mny = 3.4e38f, mxx = -3.4e38f, mxy = -3.4e38f;

    for (int base = lo; base < hi; base += 64) {
        int nb = hi - base; if (nb > 64) nb = 64;
        int2 rec = make_int2(0, 0);
        if (lane < nb) rec = srec[base + lane];
        int vsn = rec.x;
        float vea = __int_as_float(rec.y);
        int full = nb & ~1;
        for (int i = 0; i < full; i += 2) {
            int   sn = __shfl(vsn, i + hi32);
            float eav = __shfl(vea, i + hi32);
            unsigned bp = *(const unsigned*)(AB + (size_t)sn * 128 + 64 + 2 * half);
            float bx = __uint_as_float(bp << 16);
            float by = __uint_as_float(bp & 0xffff0000u);
            float m0 = fmaf(eav, u2.x, acx) + bx;
            float m1 = fmaf(eav, u2.y, acy) + by;
            sx += m0; qx = fmaf(m0, m0, qx);
            sy += m1; qy = fmaf(m1, m1, qy);
            mnx = fminf(mnx, m0); mxx = fmaxf(mxx, m0);
            mny = fminf(mny, m1); mxy = fmaxf(mxy, m1);
        }
        if (nb & 1) {
            int   sn = __shfl(vsn, full);
            float eav = __shfl(vea, full);
            unsigned bp = *(const unsigned*)(AB + (size_t)sn * 128 + 64 + 2 * half);
            float bx = __uint_as_float(bp << 16);
            float by = __uint_as_float(bp & 0xffff0000u);
            float m0 = fmaf(eav, u2.x, acx) + bx;
            float m1 = fmaf(eav, u2.y, acy) + by;
            if (hi32 == 0) {
                sx += m0; qx = fmaf(m0, m0, qx);
                sy += m1; qy = fmaf(m1, m1, qy);
                mnx = fminf(mnx, m0); mxx = fmaxf(mxx, m0);
                mny = fminf(mny, m1); mxy = fmaxf(mxy, m1);
            }
        }
    }
    sx += __shfl_xor(sx, 32); sy += __shfl_xor(sy, 32);
    qx += __shfl_xor(qx, 32); qy += __shfl_xor(qy, 32);
    mnx = fminf(mnx, __shfl_xor(mnx, 32)); mny = fminf(mny, __shfl_xor(mny, 32));
    mxx = fmaxf(mxx, __shfl_xor(mxx, 32)); mxy = fmaxf(mxy, __shfl_xor(mxy, 32));

    float c1 = (cnt > 0) ? (float)cnt : 1.f;
    float inv = 1.f / c1;
    float mex = sx * inv, mey = sy * inv;
    float vx = qx * inv - mex * mex; if (vx < 0.f) vx = 0.f;
    float vy = qy * inv - mey * mey; if (vy < 0.f) vy = 0.f;
    float sdx = sqrtf(vx + 1e-5f), sdy = sqrtf(vy + 1e-5f);
    if (cnt == 0) { mnx = mny = mxx = mxy = 0.f; }

    size_t b = (size_t)n * 256 + 2 * half;
    if (hi32 == 0) {
        *(unsigned*)(agg + b)       = packbf2(mex, mey);
        *(unsigned*)(agg + b + 64)  = packbf2(mnx, mny);
    } else {
        *(unsigned*)(agg + b + 128) = packbf2(mxx, mxy);
        *(unsigned*)(agg + b + 192) = packbf2(sdx, sdy);
    }
    if (lane == 0) ampv[n] = logf(c1 + 1.f) * AVG_LOG_INV;
}

// chunked per-graph SUM of 832-dim feature vector [x | agg | agg*amp | agg/amp]
__global__ void k_greduce2(const float* __restrict__ x, const bf16* __restrict__ agg,
                           const float* __restrict__ ampv, const int* __restrict__ batch,
                           float* __restrict__ gfeat, int* __restrict__ gcnt,
                           int N, int chunk) {
    int t = threadIdx.x;  // 256
    int lo = blockIdx.x * chunk;
    int hi = lo + chunk; if (hi > N) hi = N;
    if (lo >= hi) return;
    int curg = batch[lo];
    float s1 = 0.f, s2 = 0.f, s3 = 0.f, sx = 0.f;
    int cnt = 0;
    for (int n = lo; n < hi; n++) {
        int g = batch[n];
        if (g != curg) {
            float* gf = gfeat + (size_t)curg * 832;
            atomicAdd(&gf[64 + t], s1);
            atomicAdd(&gf[320 + t], s2);
            atomicAdd(&gf[576 + t], s3);
            if (t < 64) atomicAdd(&gf[t], sx);
            if (t == 0) atomicAdd(&gcnt[curg], cnt);
            s1 = s2 = s3 = sx = 0.f; cnt = 0; curg = g;
        }
        float amp = ampv[n];
        float av = b2f(agg[(size_t)n * 256 + t]);
        s1 += av; s2 += av * amp; s3 += av / amp;
        if (t < 64) sx += x[(size_t)n * 64 + t];
        cnt++;
    }
    float* gf = gfeat + (size_t)curg * 832;
    atomicAdd(&gf[64 + t], s1);
    atomicAdd(&gf[320 + t], s2);
    atomicAdd(&gf[576 + t], s3);
    if (t < 64) atomicAdd(&gf[t], sx);
    if (t == 0) atomicAdd(&gcnt[curg], cnt);
}

// Zin[g] = ((gfeat[g]/cnt) @ W_post + b_post) @ W_lin + b_lin ; zero if empty graph
__global__ void k_post1(const float* __restrict__ gfeat, const int* __restrict__ gcnt,
                        const float* __restrict__ W_post, const float* __restrict__ b_post,
                        const float* __restrict__ W_lin, const float* __restrict__ b_lin,
                        float* __restrict__ Zin) {
    int g = blockIdx.x, j = threadIdx.x;  // 128
    __shared__ float feat[832];
    __shared__ float z1[128];
    int cg = gcnt[g];
    float r = 1.f / ((cg > 0) ? (float)cg : 1.f);
    for (int i = j; i < 832; i += 128) feat[i] = gfeat[(size_t)g * 832 + i] * r;
    __syncthreads();
    float acc = b_post[j];
    for (int k = 0; k < 832; k++) acc += feat[k] * W_post[k * 128 + j];
    z1[j] = acc;
    __syncthreads();
    float a2 = b_lin[j];
    for (int k = 0; k < 128; k++) a2 += z1[k] * W_lin[k * 128 + j];
    if (cg == 0) a2 = 0.f;
    Zin[g * 128 + j] = a2;
}

// column-parallel MLP layer: block j computes output column j of
//   out = relu( BN(in' @ W + bias; gamma,beta) [+ res] )
// where in' = relu(BN(in; g_in,be_in)) if g_in!=nullptr else in.
// Weights read via wave-uniform (scalar) loads; BN over 64 rows done in-wave.
__global__ void k_mlpcol(const float* __restrict__ in, const float* __restrict__ W,
                         const float* __restrict__ bias,
                         const float* __restrict__ gamma, const float* __restrict__ beta,
                         const float* __restrict__ res,
                         const float* __restrict__ g_in, const float* __restrict__ be_in,
                         float* __restrict__ outp) {
    __shared__ float A[64 * 129];
    __shared__ float part[4 * 64];
    int t = threadIdx.x;  // 256
    int j = blockIdx.x;   // 128

    for (int i = t; i < 8192; i += 256) A[(i >> 7) * 129 + (i & 127)] = in[i];
    __syncthreads();

    if (g_in) {  // BN+relu the input matrix in LDS (redundant per block, cheap)
        if (t < 128) {
            int c = t;
            float mu = 0.f;
            for (int r = 0; r < 64; r++) mu += A[r * 129 + c];
            mu *= (1.f / 64.f);
            float var = 0.f;
            for (int r = 0; r < 64; r++) { float d = A[r * 129 + c] - mu; var += d * d; }
            var *= (1.f / 64.f);
            float sc = rsqrtf(var + 1e-5f) * g_in[c], sh = be_in[c];
            for (int r = 0; r < 64; r++) {
                float v = (A[r * 129 + c] - mu) * sc + sh;
                A[r * 129 + c] = v > 0.f ? v : 0.f;
            }
        }
        __syncthreads();
    }

    int r = t & 63, q = t >> 6;  // wave q handles k-chunk q; lanes = rows
    float acc = 0.f;
    int k0 = q * 32;
    #pragma unroll
    for (int k = 0; k < 32; k++) acc += A[r * 129 + k0 + k] * W[(k0 + k) * 128 + j];
    part[q * 64 + r] = acc;
    __syncthreads();

    if (t < 64) {
        float v = part[t] + part[64 + t] + part[128 + t] + part[192 + t] + bias[j];
        float mu = wave_sum(v) * (1.f / 64.f);
        float d = v - mu;
        float var = wave_sum(d * d) * (1.f / 64.f);
        float o = d * rsqrtf(var + 1e-5f) * gamma[j] + beta[j];
        if (res) o += res[t * 128 + j];
        outp[t * 128 + j] = o > 0.f ? o : 0.f;
    }
}

__global__ void k_out(const float* __restrict__ z4, const float* __restrict__ W_out,
                      const float* b_out, float* __restrict__ out) {
    int g = threadIdx.x;  // 64
    float acc = b_out[0];
    for (int j = 0; j < 128; j++) acc += z4[g * 128 + j] * W_out[j];
    out[g] = acc;
}

extern "C" void kernel_launch(void* const* d_in, const int* in_sizes, int n_in,
                              void* d_out, int out_size, void* d_ws, size_t ws_size,
                              hipStream_t stream) {
    const float* x      = (const float*)d_in[0];
    const int*   ei     = (const int*)d_in[1];
    const float* ea     = (const float*)d_in[2];
    const int*   batch  = (const int*)d_in[3];
    const float* W_edge = (const float*)d_in[4];
    const float* b_edge = (const float*)d_in[5];
    const float* W_pre  = (const float*)d_in[6];
    const float* b_pre  = (const float*)d_in[7];
    const float* W_post = (const float*)d_in[8];
    const float* b_post = (const float*)d_in[9];
    const float* W_lin  = (const float*)d_in[10];
    const float* b_lin  = (const float*)d_in[11];
    const float* g1     = (const float*)d_in[12];
    const float* be1    = (const float*)d_in[13];
    const float* W2     = (const float*)d_in[14];
    const float* b2     = (const float*)d_in[15];
    const float* g2     = (const float*)d_in[16];
    const float* be2    = (const float*)d_in[17];
    const float* Wr1    = (const float*)d_in[18];
    const float* br1    = (const float*)d_in[19];
    const float* gr1    = (const float*)d_in[20];
    const float* ber1   = (const float*)d_in[21];
    const float* Wr2    = (const float*)d_in[22];
    const float* br2    = (const float*)d_in[23];
    const float* gr2    = (const float*)d_in[24];
    const float* ber2   = (const float*)d_in[25];
    const float* W_out  = (const float*)d_in[26];
    const float* b_out  = (const float*)d_in[27];
    float* out = (float*)d_out;

    const int N = in_sizes[0] / F;      // 50000
    const int E = in_sizes[1] / 2;      // 800000
    const int G = out_size;             // 64

    char* p = (char*)d_ws;
    auto alloc = [&](size_t nbytes) { void* r = p; p += (nbytes + 255) & ~(size_t)255; return r; };
    bf16*  AB     = (bf16*)alloc((size_t)N * 128 * sizeof(bf16));
    bf16*  agg    = (bf16*)alloc((size_t)N * 256 * sizeof(bf16));
    float* ampv   = (float*)alloc((size_t)N * sizeof(float));
    int*   cnt    = (int*)alloc((size_t)N * sizeof(int));
    int*   offs   = (int*)alloc((size_t)(N + 1) * sizeof(int));
    int*   cursor = (int*)alloc((size_t)N * sizeof(int));
    int*   csum   = (int*)alloc(512 * sizeof(int));
    int2*  srec   = (int2*)alloc((size_t)E * sizeof(int2));
    float* uc     = (float*)alloc(128 * sizeof(float));
    float* gfeat  = (float*)alloc((size_t)G * 832 * sizeof(float));
    int*   gcnt   = (int*)alloc((size_t)G * sizeof(int));
    float* Zin    = (float*)alloc(64 * 128 * sizeof(float));
    float* z2b    = (float*)alloc(64 * 128 * sizeof(float));
    float* z3b    = (float*)alloc(64 * 128 * sizeof(float));
    float* z4b    = (float*)alloc(64 * 128 * sizeof(float));

    const int NCH = (N + 255) / 256;    // 196 (must be <= 256)
    const int EB = (E + 255) / 256;
    const int AB_BLOCKS = 1024, HIST_BLOCKS = 512;
    const int GRB = 512;
    const int GRCH = (N + GRB - 1) / GRB;

    k_init<<<NCH + 1, 256, 0, stream>>>(cnt, gfeat, gcnt, N, G * 832, G,
                                        W_edge, b_edge, W_pre, b_pre, uc);
    k_abhist<<<AB_BLOCKS + HIST_BLOCKS, 256, 0, stream>>>(x, W_pre, AB, N, ei, cnt, E, AB_BLOCKS);
    k_scan1<<<NCH, 256, 0, stream>>>(cnt, csum, N);
    k_scan2<<<1, 256, 0, stream>>>(csum, NCH);
    k_scan3<<<NCH, 256, 0, stream>>>(cnt, csum, offs, cursor, N, E);
    k_scatter<<<EB, 256, 0, stream>>>(ei, ea, cursor, srec, E);
    k_edge<<<(N * 64 + 255) / 256, 256, 0, stream>>>(AB, offs, srec, uc, agg, ampv, N);
    k_greduce2<<<GRB, 256, 0, stream>>>(x, agg, ampv, batch, gfeat, gcnt, N, GRCH);
    k_post1<<<G, 128, 0, stream>>>(gfeat, gcnt, W_post, b_post, W_lin, b_lin, Zin);
    // tail: z2 = relu(bn2(relu(bn1(Zin))@W2+b2)); z3 = relu(bn(z2@Wr1+br1));
    //       z4 = relu(bn(z3@Wr2+br2) + z2); out = z4@W_out + b_out
    k_mlpcol<<<HG, 256, 0, stream>>>(Zin, W2, b2, g2, be2, nullptr, g1, be1, z2b);
    k_mlpcol<<<HL, 256, 0, stream>>>(z2b, Wr1, br1, gr1, ber1, nullptr, nullptr, nullptr, z3b);
    k_mlpcol<<<HL, 256, 0, stream>>>(z3b, Wr2, br2, gr2, ber2, z2b, nullptr, nullptr, z4b);
    k_out<<<1, 64, 0, stream>>>(z4b, W_out, b_out, out);
}

// Round 6
// 342.320 us; speedup vs baseline: 1.4964x; 1.1409x over previous
//
#include <hip/hip_runtime.h>
#include <hip/hip_bf16.h>

using bf16 = __hip_bfloat16;

#define F 64
#define HG 128
#define HL 128
#define AVG_LOG_INV 0.45511961331341866f  // 1/log(9)

typedef short short8 __attribute__((ext_vector_type(8)));
typedef float floatx4 __attribute__((ext_vector_type(4)));

__device__ __forceinline__ float b2f(bf16 v) { return __bfloat162float(v); }
__device__ __forceinline__ bf16 f2b(float v) { return __float2bfloat16(v); }
__device__ __forceinline__ short f2bs(float v) { bf16 h = f2b(v); return *(short*)&h; }

__device__ __forceinline__ unsigned packbf2(float x, float y) {
    bf16 a = f2b(x), b = f2b(y);
    unsigned short ua = *(unsigned short*)&a, ub = *(unsigned short*)&b;
    return ((unsigned)ub << 16) | (unsigned)ua;
}

__device__ __forceinline__ float wave_sum(float v) {
    #pragma unroll
    for (int m = 32; m > 0; m >>= 1) v += __shfl_xor(v, m);
    return v;
}

// fused: zero cnt/gfeat/gcnt + compute uc[128] in the last block
__global__ void k_init(int* __restrict__ cnt, float* __restrict__ gfeat,
                       int* __restrict__ gcnt, int N, int GF, int G,
                       const float* __restrict__ W_edge, const float* __restrict__ b_edge,
                       const float* __restrict__ W_pre, const float* __restrict__ b_pre,
                       float* __restrict__ uc) {
    if (blockIdx.x == gridDim.x - 1) {
        int f = threadIdx.x;
        if (f < 64) {
            float u = 0.f, c = b_pre[f];
            for (int k = 0; k < 64; k++) {
                float w3 = W_pre[(128 + k) * 64 + f];
                u += W_edge[k] * w3;
                c += b_edge[k] * w3;
            }
            uc[f] = u; uc[64 + f] = c;
        } else if (f - 64 < G) {
            gcnt[f - 64] = 0;
        }
        return;
    }
    int i = blockIdx.x * 256 + threadIdx.x;
    if (i < N) cnt[i] = 0;
    if (i < GF) gfeat[i] = 0.f;
}

// degree histogram, int4-vectorized edge reads
__global__ void k_hist(const int* __restrict__ ei, int* __restrict__ cnt, int E) {
    int nq = E >> 2;
    int stride = gridDim.x * blockDim.x;
    const int4* p = (const int4*)(ei + E);
    for (int i = blockIdx.x * blockDim.x + threadIdx.x; i < nq; i += stride) {
        int4 d = p[i];
        atomicAdd(&cnt[d.x], 1);
        atomicAdd(&cnt[d.y], 1);
        atomicAdd(&cnt[d.z], 1);
        atomicAdd(&cnt[d.w], 1);
    }
    if (blockIdx.x == 0 && threadIdx.x == 0)
        for (int e = nq << 2; e < E; e++) atomicAdd(&cnt[ei[E + e]], 1);
}

// MFMA AB staging: AB[n][0:64] = x[n]@W1, AB[n][64:128] = x[n]@W2  (bf16)
// wave = 16 nodes x 128 features; A from global, B via ds_read_b128 from
// transposed bf16 W in LDS (row stride 72 to break bank conflicts).
__global__ void k_ab_mfma(const float* __restrict__ x, const float* __restrict__ W_pre,
                          bf16* __restrict__ AB, int N) {
    __shared__ unsigned short wt[128 * 72];  // wt[m][k]: m=out feat 0..127, k=0..63
    for (int idx = threadIdx.x; idx < 8192; idx += 256) {
        int k = idx >> 7, m = idx & 127;
        float v = W_pre[((m & 64) + k) * 64 + (m & 63)];
        wt[m * 72 + k] = (unsigned short)f2bs(v);
    }
    __syncthreads();

    int lane = threadIdx.x & 63;
    int row = lane & 15, quad = lane >> 4;
    int w = (blockIdx.x * blockDim.x + threadIdx.x) >> 6;
    int nwaves = (gridDim.x * blockDim.x) >> 6;
    int ntiles = (N + 15) >> 4;

    for (int tile = w; tile < ntiles; tile += nwaves) {
        int m0 = tile << 4;
        int node_a = m0 + row; if (node_a >= N) node_a = N - 1;
        short8 a[2];
        #pragma unroll
        for (int h = 0; h < 2; h++) {
            const float* xp = x + (size_t)node_a * 64 + h * 32 + quad * 8;
            floatx4 v0 = *(const floatx4*)xp;
            floatx4 v1 = *(const floatx4*)(xp + 4);
            #pragma unroll
            for (int j = 0; j < 4; j++) { a[h][j] = f2bs(v0[j]); a[h][4 + j] = f2bs(v1[j]); }
        }
        #pragma unroll
        for (int t = 0; t < 8; t++) {
            int fbase = t * 16;  // output features fbase..fbase+15
            floatx4 c = {0.f, 0.f, 0.f, 0.f};
            #pragma unroll
            for (int h = 0; h < 2; h++) {
                short8 b = *(const short8*)(wt + (fbase + row) * 72 + h * 32 + quad * 8);
                c = __builtin_amdgcn_mfma_f32_16x16x32_bf16(a[h], b, c, 0, 0, 0);
            }
            #pragma unroll
            for (int r = 0; r < 4; r++) {
                int node = m0 + quad * 4 + r;
                if (node < N) AB[(size_t)node * 128 + fbase + row] = f2b(c[r]);
            }
        }
    }
}

__global__ void k_scan1(const int* __restrict__ cnt, int* __restrict__ csum, int N) {
    __shared__ int s[256];
    int i = blockIdx.x * 256 + threadIdx.x;
    s[threadIdx.x] = (i < N) ? cnt[i] : 0;
    __syncthreads();
    for (int st = 128; st > 0; st >>= 1) {
        if (threadIdx.x < st) s[threadIdx.x] += s[threadIdx.x + st];
        __syncthreads();
    }
    if (threadIdx.x == 0) csum[blockIdx.x] = s[0];
}

// exclusive scan of csum[0..NCH), NCH <= 256
__global__ void k_scan2(int* csum, int NCH) {
    __shared__ int s[256];
    int t = threadIdx.x;
    int v = (t < NCH) ? csum[t] : 0;
    s[t] = v;
    __syncthreads();
    for (int st = 1; st < 256; st <<= 1) {
        int a = (t >= st) ? s[t - st] : 0;
        __syncthreads();
        s[t] += a;
        __syncthreads();
    }
    if (t < NCH) csum[t] = s[t] - v;
}

__global__ void k_scan3(const int* __restrict__ cnt, const int* __restrict__ csum,
                        int* __restrict__ offs, int* __restrict__ cursor, int N, int E) {
    __shared__ int s[256];
    int t = threadIdx.x;
    int i = blockIdx.x * 256 + t;
    int v = (i < N) ? cnt[i] : 0;
    s[t] = v;
    __syncthreads();
    for (int st = 1; st < 256; st <<= 1) {
        int a = (t >= st) ? s[t - st] : 0;
        __syncthreads();
        s[t] += a;
        __syncthreads();
    }
    int excl = s[t] - v + csum[blockIdx.x];
    if (i < N) { offs[i] = excl; cursor[i] = excl; }
    if (i == 0) offs[N] = E;
}

// packed edge record: (src node, edge_attr bits) — one 8B store per edge
__global__ void k_scatter(const int* __restrict__ ei, const float* __restrict__ ea,
                          int* __restrict__ cursor, int2* __restrict__ srec, int E) {
    int e = blockIdx.x * blockDim.x + threadIdx.x;
    if (e >= E) return;
    int d = ei[E + e];
    int p = atomicAdd(&cursor[d], 1);
    srec[p] = make_int2(ei[e], __float_as_int(ea[e]));
}

// one wave per node; lanes split 32/32 over two edges per iteration,
// each lane handles a bf16x2 feature pair; edge records batched via lane loads + shfl
__global__ void k_edge(const bf16* __restrict__ AB, const int* __restrict__ offs,
                       const int2* __restrict__ srec, const float* __restrict__ uc,
                       bf16* __restrict__ agg, float* __restrict__ ampv, int N) {
    int lane = threadIdx.x & 63;
    int n = (blockIdx.x * blockDim.x + threadIdx.x) >> 6;
    if (n >= N) return;
    int lo = offs[n], hi = offs[n + 1];
    int cnt = hi - lo;
    int half = lane & 31;   // feature-pair index (features 2*half, 2*half+1)
    int hi32 = lane >> 5;   // which edge of the pair

    unsigned apack = *(const unsigned*)(AB + (size_t)n * 128 + 2 * half);
    float ax = __uint_as_float(apack << 16);
    float ay = __uint_as_float(apack & 0xffff0000u);
    float2 u2 = *(const float2*)(uc + 2 * half);
    float2 c2 = *(const float2*)(uc + 64 + 2 * half);
    float acx = ax + c2.x, acy = ay + c2.y;

    float sx = 0.f, sy = 0.f, qx = 0.f, qy = 0.f;
    float mnx = 3.4e38f, mny = 3.4e38f, mxx = -3.4e38f, mxy = -3.4e38f;

    for (int base = lo; base < hi; base += 64) {
        int nb = hi - base; if (nb > 64) nb = 64;
        int2 rec = make_int2(0, 0);
        if (lane < nb) rec = srec[base + lane];
        int vsn = rec.x;
        float vea = __int_as_float(rec.y);
        int full = nb & ~1;
        for (int i = 0; i < full; i += 2) {
            int   sn = __shfl(vsn, i + hi32);
            float eav = __shfl(vea, i + hi32);
            unsigned bp = *(const unsigned*)(AB + (size_t)sn * 128 + 64 + 2 * half);
            float bx = __uint_as_float(bp << 16);
            float by = __uint_as_float(bp & 0xffff0000u);
            float m0 = fmaf(eav, u2.x, acx) + bx;
            float m1 = fmaf(eav, u2.y, acy) + by;
            sx += m0; qx = fmaf(m0, m0, qx);
            sy += m1; qy = fmaf(m1, m1, qy);
            mnx = fminf(mnx, m0); mxx = fmaxf(mxx, m0);
            mny = fminf(mny, m1); mxy = fmaxf(mxy, m1);
        }
        if (nb & 1) {
            int   sn = __shfl(vsn, full);
            float eav = __shfl(vea, full);
            unsigned bp = *(const unsigned*)(AB + (size_t)sn * 128 + 64 + 2 * half);
            float bx = __uint_as_float(bp << 16);
            float by = __uint_as_float(bp & 0xffff0000u);
            float m0 = fmaf(eav, u2.x, acx) + bx;
            float m1 = fmaf(eav, u2.y, acy) + by;
            if (hi32 == 0) {
                sx += m0; qx = fmaf(m0, m0, qx);
                sy += m1; qy = fmaf(m1, m1, qy);
                mnx = fminf(mnx, m0); mxx = fmaxf(mxx, m0);
                mny = fminf(mny, m1); mxy = fmaxf(mxy, m1);
            }
        }
    }
    sx += __shfl_xor(sx, 32); sy += __shfl_xor(sy, 32);
    qx += __shfl_xor(qx, 32); qy += __shfl_xor(qy, 32);
    mnx = fminf(mnx, __shfl_xor(mnx, 32)); mny = fminf(mny, __shfl_xor(mny, 32));
    mxx = fmaxf(mxx, __shfl_xor(mxx, 32)); mxy = fmaxf(mxy, __shfl_xor(mxy, 32));

    float c1 = (cnt > 0) ? (float)cnt : 1.f;
    float inv = 1.f / c1;
    float mex = sx * inv, mey = sy * inv;
    float vx = qx * inv - mex * mex; if (vx < 0.f) vx = 0.f;
    float vy = qy * inv - mey * mey; if (vy < 0.f) vy = 0.f;
    float sdx = sqrtf(vx + 1e-5f), sdy = sqrtf(vy + 1e-5f);
    if (cnt == 0) { mnx = mny = mxx = mxy = 0.f; }

    size_t b = (size_t)n * 256 + 2 * half;
    if (hi32 == 0) {
        *(unsigned*)(agg + b)       = packbf2(mex, mey);
        *(unsigned*)(agg + b + 64)  = packbf2(mnx, mny);
    } else {
        *(unsigned*)(agg + b + 128) = packbf2(mxx, mxy);
        *(unsigned*)(agg + b + 192) = packbf2(sdx, sdy);
    }
    if (lane == 0) ampv[n] = logf(c1 + 1.f) * AVG_LOG_INV;
}

// chunked per-graph SUM of 832-dim feature vector [x | agg | agg*amp | agg/amp]
__global__ void k_greduce2(const float* __restrict__ x, const bf16* __restrict__ agg,
                           const float* __restrict__ ampv, const int* __restrict__ batch,
                           float* __restrict__ gfeat, int* __restrict__ gcnt,
                           int N, int chunk) {
    int t = threadIdx.x;  // 256
    int lo = blockIdx.x * chunk;
    int hi = lo + chunk; if (hi > N) hi = N;
    if (lo >= hi) return;
    int curg = batch[lo];
    float s1 = 0.f, s2 = 0.f, s3 = 0.f, sx = 0.f;
    int cnt = 0;
    for (int n = lo; n < hi; n++) {
        int g = batch[n];
        if (g != curg) {
            float* gf = gfeat + (size_t)curg * 832;
            atomicAdd(&gf[64 + t], s1);
            atomicAdd(&gf[320 + t], s2);
            atomicAdd(&gf[576 + t], s3);
            if (t < 64) atomicAdd(&gf[t], sx);
            if (t == 0) atomicAdd(&gcnt[curg], cnt);
            s1 = s2 = s3 = sx = 0.f; cnt = 0; curg = g;
        }
        float amp = ampv[n];
        float av = b2f(agg[(size_t)n * 256 + t]);
        s1 += av; s2 += av * amp; s3 += av / amp;
        if (t < 64) sx += x[(size_t)n * 64 + t];
        cnt++;
    }
    float* gf = gfeat + (size_t)curg * 832;
    atomicAdd(&gf[64 + t], s1);
    atomicAdd(&gf[320 + t], s2);
    atomicAdd(&gf[576 + t], s3);
    if (t < 64) atomicAdd(&gf[t], sx);
    if (t == 0) atomicAdd(&gcnt[curg], cnt);
}

// Zin[g] = ((gfeat[g]/cnt) @ W_post + b_post) @ W_lin + b_lin ; zero if empty graph
__global__ void k_post1(const float* __restrict__ gfeat, const int* __restrict__ gcnt,
                        const float* __restrict__ W_post, const float* __restrict__ b_post,
                        const float* __restrict__ W_lin, const float* __restrict__ b_lin,
                        float* __restrict__ Zin) {
    int g = blockIdx.x, j = threadIdx.x;  // 128
    __shared__ float feat[832];
    __shared__ float z1[128];
    int cg = gcnt[g];
    float r = 1.f / ((cg > 0) ? (float)cg : 1.f);
    for (int i = j; i < 832; i += 128) feat[i] = gfeat[(size_t)g * 832 + i] * r;
    __syncthreads();
    float acc = b_post[j];
    for (int k = 0; k < 832; k++) acc += feat[k] * W_post[k * 128 + j];
    z1[j] = acc;
    __syncthreads();
    float a2 = b_lin[j];
    for (int k = 0; k < 128; k++) a2 += z1[k] * W_lin[k * 128 + j];
    if (cg == 0) a2 = 0.f;
    Zin[g * 128 + j] = a2;
}

// column-parallel MLP layer: block j computes output column j of
//   out = relu( BN(in' @ W + bias; gamma,beta) [+ res] ), in' = relu(BN(in)) if g_in
__global__ void k_mlpcol(const float* __restrict__ in, const float* __restrict__ W,
                         const float* __restrict__ bias,
                         const float* __restrict__ gamma, const float* __restrict__ beta,
                         const float* __restrict__ res,
                         const float* __restrict__ g_in, const float* __restrict__ be_in,
                         float* __restrict__ outp) {
    __shared__ float A[64 * 129];
    __shared__ float part[4 * 64];
    int t = threadIdx.x;  // 256
    int j = blockIdx.x;   // 128

    for (int i = t; i < 8192; i += 256) A[(i >> 7) * 129 + (i & 127)] = in[i];
    __syncthreads();

    if (g_in) {
        if (t < 128) {
            int c = t;
            float mu = 0.f;
            for (int r = 0; r < 64; r++) mu += A[r * 129 + c];
            mu *= (1.f / 64.f);
            float var = 0.f;
            for (int r = 0; r < 64; r++) { float d = A[r * 129 + c] - mu; var += d * d; }
            var *= (1.f / 64.f);
            float sc = rsqrtf(var + 1e-5f) * g_in[c], sh = be_in[c];
            for (int r = 0; r < 64; r++) {
                float v = (A[r * 129 + c] - mu) * sc + sh;
                A[r * 129 + c] = v > 0.f ? v : 0.f;
            }
        }
        __syncthreads();
    }

    int r = t & 63, q = t >> 6;
    float acc = 0.f;
    int k0 = q * 32;
    #pragma unroll
    for (int k = 0; k < 32; k++) acc += A[r * 129 + k0 + k] * W[(k0 + k) * 128 + j];
    part[q * 64 + r] = acc;
    __syncthreads();

    if (t < 64) {
        float v = part[t] + part[64 + t] + part[128 + t] + part[192 + t] + bias[j];
        float mu = wave_sum(v) * (1.f / 64.f);
        float d = v - mu;
        float var = wave_sum(d * d) * (1.f / 64.f);
        float o = d * rsqrtf(var + 1e-5f) * gamma[j] + beta[j];
        if (res) o += res[t * 128 + j];
        outp[t * 128 + j] = o > 0.f ? o : 0.f;
    }
}

__global__ void k_out(const float* __restrict__ z4, const float* __restrict__ W_out,
                      const float* b_out, float* __restrict__ out) {
    int g = threadIdx.x;  // 64
    float acc = b_out[0];
    for (int j = 0; j < 128; j++) acc += z4[g * 128 + j] * W_out[j];
    out[g] = acc;
}

extern "C" void kernel_launch(void* const* d_in, const int* in_sizes, int n_in,
                              void* d_out, int out_size, void* d_ws, size_t ws_size,
                              hipStream_t stream) {
    const float* x      = (const float*)d_in[0];
    const int*   ei     = (const int*)d_in[1];
    const float* ea     = (const float*)d_in[2];
    const int*   batch  = (const int*)d_in[3];
    const float* W_edge = (const float*)d_in[4];
    const float* b_edge = (const float*)d_in[5];
    const float* W_pre  = (const float*)d_in[6];
    const float* b_pre  = (const float*)d_in[7];
    const float* W_post = (const float*)d_in[8];
    const float* b_post = (const float*)d_in[9];
    const float* W_lin  = (const float*)d_in[10];
    const float* b_lin  = (const float*)d_in[11];
    const float* g1     = (const float*)d_in[12];
    const float* be1    = (const float*)d_in[13];
    const float* W2     = (const float*)d_in[14];
    const float* b2     = (const float*)d_in[15];
    const float* g2     = (const float*)d_in[16];
    const float* be2    = (const float*)d_in[17];
    const float* Wr1    = (const float*)d_in[18];
    const float* br1    = (const float*)d_in[19];
    const float* gr1    = (const float*)d_in[20];
    const float* ber1   = (const float*)d_in[21];
    const float* Wr2    = (const float*)d_in[22];
    const float* br2    = (const float*)d_in[23];
    const float* gr2    = (const float*)d_in[24];
    const float* ber2   = (const float*)d_in[25];
    const float* W_out  = (const float*)d_in[26];
    const float* b_out  = (const float*)d_in[27];
    float* out = (float*)d_out;

    const int N = in_sizes[0] / F;      // 50000
    const int E = in_sizes[1] / 2;      // 800000
    const int G = out_size;             // 64

    char* p = (char*)d_ws;
    auto alloc = [&](size_t nbytes) { void* r = p; p += (nbytes + 255) & ~(size_t)255; return r; };
    bf16*  AB     = (bf16*)alloc((size_t)N * 128 * sizeof(bf16));
    bf16*  agg    = (bf16*)alloc((size_t)N * 256 * sizeof(bf16));
    float* ampv   = (float*)alloc((size_t)N * sizeof(float));
    int*   cnt    = (int*)alloc((size_t)N * sizeof(int));
    int*   offs   = (int*)alloc((size_t)(N + 1) * sizeof(int));
    int*   cursor = (int*)alloc((size_t)N * sizeof(int));
    int*   csum   = (int*)alloc(512 * sizeof(int));
    int2*  srec   = (int2*)alloc((size_t)E * sizeof(int2));
    float* uc     = (float*)alloc(128 * sizeof(float));
    float* gfeat  = (float*)alloc((size_t)G * 832 * sizeof(float));
    int*   gcnt   = (int*)alloc((size_t)G * sizeof(int));
    float* Zin    = (float*)alloc(64 * 128 * sizeof(float));
    float* z2b    = (float*)alloc(64 * 128 * sizeof(float));
    float* z3b    = (float*)alloc(64 * 128 * sizeof(float));
    float* z4b    = (float*)alloc(64 * 128 * sizeof(float));

    const int NCH = (N + 255) / 256;    // 196 (must be <= 256)
    const int EB = (E + 255) / 256;
    const int GF = G * 832;
    int initb = NCH; if ((GF + 255) / 256 > initb) initb = (GF + 255) / 256;
    const int GRB = 512;
    const int GRCH = (N + GRB - 1) / GRB;
    const int ABB = ((N + 15) / 16 + 3) / 4;   // 4 waves/block, 1 tile/wave min

    k_init<<<initb + 1, 256, 0, stream>>>(cnt, gfeat, gcnt, N, GF, G,
                                          W_edge, b_edge, W_pre, b_pre, uc);
    k_hist<<<782, 256, 0, stream>>>(ei, cnt, E);
    k_ab_mfma<<<ABB, 256, 0, stream>>>(x, W_pre, AB, N);
    k_scan1<<<NCH, 256, 0, stream>>>(cnt, csum, N);
    k_scan2<<<1, 256, 0, stream>>>(csum, NCH);
    k_scan3<<<NCH, 256, 0, stream>>>(cnt, csum, offs, cursor, N, E);
    k_scatter<<<EB, 256, 0, stream>>>(ei, ea, cursor, srec, E);
    k_edge<<<(N * 64 + 255) / 256, 256, 0, stream>>>(AB, offs, srec, uc, agg, ampv, N);
    k_greduce2<<<GRB, 256, 0, stream>>>(x, agg, ampv, batch, gfeat, gcnt, N, GRCH);
    k_post1<<<G, 128, 0, stream>>>(gfeat, gcnt, W_post, b_post, W_lin, b_lin, Zin);
    k_mlpcol<<<HG, 256, 0, stream>>>(Zin, W2, b2, g2, be2, nullptr, g1, be1, z2b);
    k_mlpcol<<<HL, 256, 0, stream>>>(z2b, Wr1, br1, gr1, ber1, nullptr, nullptr, nullptr, z3b);
    k_mlpcol<<<HL, 256, 0, stream>>>(z3b, Wr2, br2, gr2, ber2, z2b, nullptr, nullptr, z4b);
    k_out<<<1, 64, 0, stream>>>(z4b, W_out, b_out, out);
}

// Round 7
// 296.984 us; speedup vs baseline: 1.7249x; 1.1527x over previous
//
#include <hip/hip_runtime.h>
#include <hip/hip_bf16.h>

using bf16 = __hip_bfloat16;

#define F 64
#define HG 128
#define HL 128
#define AVG_LOG_INV 0.45511961331341866f  // 1/log(9)
#define BCAP 1536        // per-bucket record capacity (mean 1024, +16 sigma)
#define BTILE 8192       // edges per k_bucket block

typedef short short8 __attribute__((ext_vector_type(8)));
typedef float floatx4 __attribute__((ext_vector_type(4)));

__device__ __forceinline__ float b2f(bf16 v) { return __bfloat162float(v); }
__device__ __forceinline__ bf16 f2b(float v) { return __float2bfloat16(v); }
__device__ __forceinline__ short f2bs(float v) { bf16 h = f2b(v); return *(short*)&h; }

__device__ __forceinline__ unsigned packbf2(float x, float y) {
    bf16 a = f2b(x), b = f2b(y);
    unsigned short ua = *(unsigned short*)&a, ub = *(unsigned short*)&b;
    return ((unsigned)ub << 16) | (unsigned)ua;
}

__device__ __forceinline__ float wave_sum(float v) {
    #pragma unroll
    for (int m = 32; m > 0; m >>= 1) v += __shfl_xor(v, m);
    return v;
}

// fused: zero gcur/gfeat/gcnt + compute uc[128] in the last block
__global__ void k_init(int* __restrict__ gcur, float* __restrict__ gfeat,
                       int* __restrict__ gcnt, int NB, int GF, int G,
                       const float* __restrict__ W_edge, const float* __restrict__ b_edge,
                       const float* __restrict__ W_pre, const float* __restrict__ b_pre,
                       float* __restrict__ uc) {
    if (blockIdx.x == gridDim.x - 1) {
        int f = threadIdx.x;
        if (f < 64) {
            float u = 0.f, c = b_pre[f];
            for (int k = 0; k < 64; k++) {
                float w3 = W_pre[(128 + k) * 64 + f];
                u += W_edge[k] * w3;
                c += b_edge[k] * w3;
            }
            uc[f] = u; uc[64 + f] = c;
        } else if (f - 64 < G) {
            gcnt[f - 64] = 0;
        }
        return;
    }
    int i = blockIdx.x * 256 + threadIdx.x;
    if (i < NB) gcur[i] = 0;
    if (i < GF) gfeat[i] = 0.f;
}

// MFMA AB staging: AB[n][0:64] = x[n]@W1, AB[n][64:128] = x[n]@W2  (bf16)
__global__ void k_ab_mfma(const float* __restrict__ x, const float* __restrict__ W_pre,
                          bf16* __restrict__ AB, int N) {
    __shared__ unsigned short wt[128 * 72];  // wt[m][k]
    for (int idx = threadIdx.x; idx < 8192; idx += 256) {
        int k = idx >> 7, m = idx & 127;
        float v = W_pre[((m & 64) + k) * 64 + (m & 63)];
        wt[m * 72 + k] = (unsigned short)f2bs(v);
    }
    __syncthreads();

    int lane = threadIdx.x & 63;
    int row = lane & 15, quad = lane >> 4;
    int w = (blockIdx.x * blockDim.x + threadIdx.x) >> 6;
    int nwaves = (gridDim.x * blockDim.x) >> 6;
    int ntiles = (N + 15) >> 4;

    for (int tile = w; tile < ntiles; tile += nwaves) {
        int m0 = tile << 4;
        int node_a = m0 + row; if (node_a >= N) node_a = N - 1;
        short8 a[2];
        #pragma unroll
        for (int h = 0; h < 2; h++) {
            const float* xp = x + (size_t)node_a * 64 + h * 32 + quad * 8;
            floatx4 v0 = *(const floatx4*)xp;
            floatx4 v1 = *(const floatx4*)(xp + 4);
            #pragma unroll
            for (int j = 0; j < 4; j++) { a[h][j] = f2bs(v0[j]); a[h][4 + j] = f2bs(v1[j]); }
        }
        #pragma unroll
        for (int t = 0; t < 8; t++) {
            int fbase = t * 16;
            floatx4 c = {0.f, 0.f, 0.f, 0.f};
            #pragma unroll
            for (int h = 0; h < 2; h++) {
                short8 b = *(const short8*)(wt + (fbase + row) * 72 + h * 32 + quad * 8);
                c = __builtin_amdgcn_mfma_f32_16x16x32_bf16(a[h], b, c, 0, 0, 0);
            }
            #pragma unroll
            for (int r = 0; r < 4; r++) {
                int node = m0 + quad * 4 + r;
                if (node < N) AB[(size_t)node * 128 + fbase + row] = f2b(c[r]);
            }
        }
    }
}

// bucket partition: bucket = dst>>6 (64 nodes/bucket). LDS-aggregated cursor
// reservations (one global atomic per tile x bucket); records land in hot
// per-bucket L2 ranges -> writes merge. rec = ((dst<<16)|src, ea_f32bits).
// REQUIRES N <= 65536.
__global__ void k_bucket(const int* __restrict__ ei, const float* __restrict__ ea,
                         int* __restrict__ gcur, int2* __restrict__ gout,
                         int E, int NB) {
    __shared__ int2 recs[BTILE];
    __shared__ int hist[800], gst[800], lrk[800];
    int t = threadIdx.x;
    for (int b = t; b < NB; b += 256) hist[b] = 0;
    __syncthreads();
    int base = blockIdx.x * BTILE;
    int lim = E - base; if (lim > BTILE) lim = BTILE;
    for (int i = t; i < lim; i += 256) {
        int e = base + i;
        int src = ei[e], dst = ei[E + e];
        recs[i] = make_int2((dst << 16) | src, __float_as_int(ea[e]));
        atomicAdd(&hist[dst >> 6], 1);
    }
    __syncthreads();
    for (int b = t; b < NB; b += 256) {
        int h = hist[b];
        lrk[b] = 0;
        gst[b] = (h > 0) ? atomicAdd(&gcur[b], h) : 0;
    }
    __syncthreads();
    for (int i = t; i < lim; i += 256) {
        int2 r = recs[i];
        int b = ((unsigned)r.x) >> 22;
        int k = atomicAdd(&lrk[b], 1);
        int pos = gst[b] + k;
        if (pos < BCAP) gout[(size_t)b * BCAP + pos] = r;
    }
}

// one block per bucket: LDS counting-sort records by node, then per-node
// reduction (wave per node; lanes = feature pairs, 2 edges per iteration)
__global__ void k_edge(const bf16* __restrict__ AB, const int2* __restrict__ gout,
                       const int* __restrict__ gcur, const float* __restrict__ uc,
                       bf16* __restrict__ agg, float* __restrict__ ampv, int N) {
    __shared__ int2 recs[BCAP], sortd[BCAP];
    __shared__ int ncnt[64], nofs[64], nrank[64];
    int t = threadIdx.x;
    int b = blockIdx.x;
    int nn = N - b * 64; if (nn > 64) nn = 64;
    int ecnt = gcur[b]; if (ecnt > BCAP) ecnt = BCAP;

    for (int i = t; i < ecnt; i += 256) recs[i] = gout[(size_t)b * BCAP + i];
    if (t < 64) { ncnt[t] = 0; nrank[t] = 0; }
    __syncthreads();
    for (int i = t; i < ecnt; i += 256)
        atomicAdd(&ncnt[((unsigned)recs[i].x >> 16) & 63], 1);
    __syncthreads();
    if (t < 64) {  // wave 0: exclusive scan over 64 node counts
        int v = ncnt[t], inc = v;
        #pragma unroll
        for (int m = 1; m < 64; m <<= 1) { int u = __shfl_up(inc, m); if (t >= m) inc += u; }
        nofs[t] = inc - v;
    }
    __syncthreads();
    for (int i = t; i < ecnt; i += 256) {
        int2 r = recs[i];
        int nl = ((unsigned)r.x >> 16) & 63;
        int k = atomicAdd(&nrank[nl], 1);
        sortd[nofs[nl] + k] = r;
    }
    __syncthreads();

    int lane = t & 63, w = t >> 6;
    int half = lane & 31, hi32 = lane >> 5;
    float2 u2 = *(const float2*)(uc + 2 * half);
    float2 c2 = *(const float2*)(uc + 64 + 2 * half);

    for (int nl = w; nl < nn; nl += 4) {
        int n = b * 64 + nl;
        int lo = nofs[nl], cnt = ncnt[nl], hi = lo + cnt;

        unsigned apack = *(const unsigned*)(AB + (size_t)n * 128 + 2 * half);
        float acx = __uint_as_float(apack << 16) + c2.x;
        float acy = __uint_as_float(apack & 0xffff0000u) + c2.y;

        float sx = 0.f, sy = 0.f, qx = 0.f, qy = 0.f;
        float mnx = 3.4e38f, mny = 3.4e38f, mxx = -3.4e38f, mxy = -3.4e38f;

        for (int base = lo; base < hi; base += 64) {
            int nb = hi - base; if (nb > 64) nb = 64;
            int2 rec = (lane < nb) ? sortd[base + lane] : make_int2(0, 0);
            int vsn = rec.x & 0xFFFF;
            float vea = __int_as_float(rec.y);
            int full = nb & ~1;
            for (int i = 0; i < full; i += 2) {
                int   sn = __shfl(vsn, i + hi32);
                float eav = __shfl(vea, i + hi32);
                unsigned bp = *(const unsigned*)(AB + (size_t)sn * 128 + 64 + 2 * half);
                float bx = __uint_as_float(bp << 16);
                float by = __uint_as_float(bp & 0xffff0000u);
                float m0 = fmaf(eav, u2.x, acx) + bx;
                float m1 = fmaf(eav, u2.y, acy) + by;
                sx += m0; qx = fmaf(m0, m0, qx);
                sy += m1; qy = fmaf(m1, m1, qy);
                mnx = fminf(mnx, m0); mxx = fmaxf(mxx, m0);
                mny = fminf(mny, m1); mxy = fmaxf(mxy, m1);
            }
            if (nb & 1) {
                int   sn = __shfl(vsn, full);
                float eav = __shfl(vea, full);
                unsigned bp = *(const unsigned*)(AB + (size_t)sn * 128 + 64 + 2 * half);
                float bx = __uint_as_float(bp << 16);
                float by = __uint_as_float(bp & 0xffff0000u);
                float m0 = fmaf(eav, u2.x, acx) + bx;
                float m1 = fmaf(eav, u2.y, acy) + by;
                if (hi32 == 0) {
                    sx += m0; qx = fmaf(m0, m0, qx);
                    sy += m1; qy = fmaf(m1, m1, qy);
                    mnx = fminf(mnx, m0); mxx = fmaxf(mxx, m0);
                    mny = fminf(mny, m1); mxy = fmaxf(mxy, m1);
                }
            }
        }
        sx += __shfl_xor(sx, 32); sy += __shfl_xor(sy, 32);
        qx += __shfl_xor(qx, 32); qy += __shfl_xor(qy, 32);
        mnx = fminf(mnx, __shfl_xor(mnx, 32)); mny = fminf(mny, __shfl_xor(mny, 32));
        mxx = fmaxf(mxx, __shfl_xor(mxx, 32)); mxy = fmaxf(mxy, __shfl_xor(mxy, 32));

        float c1 = (cnt > 0) ? (float)cnt : 1.f;
        float inv = 1.f / c1;
        float mex = sx * inv, mey = sy * inv;
        float vx = qx * inv - mex * mex; if (vx < 0.f) vx = 0.f;
        float vy = qy * inv - mey * mey; if (vy < 0.f) vy = 0.f;
        float sdx = sqrtf(vx + 1e-5f), sdy = sqrtf(vy + 1e-5f);
        if (cnt == 0) { mnx = mny = mxx = mxy = 0.f; }

        size_t ob = (size_t)n * 256 + 2 * half;
        if (hi32 == 0) {
            *(unsigned*)(agg + ob)       = packbf2(mex, mey);
            *(unsigned*)(agg + ob + 64)  = packbf2(mnx, mny);
        } else {
            *(unsigned*)(agg + ob + 128) = packbf2(mxx, mxy);
            *(unsigned*)(agg + ob + 192) = packbf2(sdx, sdy);
        }
        if (lane == 0) ampv[n] = logf(c1 + 1.f) * AVG_LOG_INV;
    }
}

// chunked per-graph SUM of 832-dim feature vector [x | agg | agg*amp | agg/amp]
__global__ void k_greduce2(const float* __restrict__ x, const bf16* __restrict__ agg,
                           const float* __restrict__ ampv, const int* __restrict__ batch,
                           float* __restrict__ gfeat, int* __restrict__ gcnt,
                           int N, int chunk) {
    int t = threadIdx.x;  // 256
    int lo = blockIdx.x * chunk;
    int hi = lo + chunk; if (hi > N) hi = N;
    if (lo >= hi) return;
    int curg = batch[lo];
    float s1 = 0.f, s2 = 0.f, s3 = 0.f, sx = 0.f;
    int cnt = 0;
    for (int n = lo; n < hi; n++) {
        int g = batch[n];
        if (g != curg) {
            float* gf = gfeat + (size_t)curg * 832;
            atomicAdd(&gf[64 + t], s1);
            atomicAdd(&gf[320 + t], s2);
            atomicAdd(&gf[576 + t], s3);
            if (t < 64) atomicAdd(&gf[t], sx);
            if (t == 0) atomicAdd(&gcnt[curg], cnt);
            s1 = s2 = s3 = sx = 0.f; cnt = 0; curg = g;
        }
        float amp = ampv[n];
        float av = b2f(agg[(size_t)n * 256 + t]);
        s1 += av; s2 += av * amp; s3 += av / amp;
        if (t < 64) sx += x[(size_t)n * 64 + t];
        cnt++;
    }
    float* gf = gfeat + (size_t)curg * 832;
    atomicAdd(&gf[64 + t], s1);
    atomicAdd(&gf[320 + t], s2);
    atomicAdd(&gf[576 + t], s3);
    if (t < 64) atomicAdd(&gf[t], sx);
    if (t == 0) atomicAdd(&gcnt[curg], cnt);
}

// Zin[g] = ((gfeat[g]/cnt) @ W_post + b_post) @ W_lin + b_lin ; zero if empty graph
__global__ void k_post1(const float* __restrict__ gfeat, const int* __restrict__ gcnt,
                        const float* __restrict__ W_post, const float* __restrict__ b_post,
                        const float* __restrict__ W_lin, const float* __restrict__ b_lin,
                        float* __restrict__ Zin) {
    int g = blockIdx.x, j = threadIdx.x;  // 128
    __shared__ float feat[832];
    __shared__ float z1[128];
    int cg = gcnt[g];
    float r = 1.f / ((cg > 0) ? (float)cg : 1.f);
    for (int i = j; i < 832; i += 128) feat[i] = gfeat[(size_t)g * 832 + i] * r;
    __syncthreads();
    float acc = b_post[j];
    for (int k = 0; k < 832; k++) acc += feat[k] * W_post[k * 128 + j];
    z1[j] = acc;
    __syncthreads();
    float a2 = b_lin[j];
    for (int k = 0; k < 128; k++) a2 += z1[k] * W_lin[k * 128 + j];
    if (cg == 0) a2 = 0.f;
    Zin[g * 128 + j] = a2;
}

// column-parallel MLP layer: block j computes output column j of
//   out = relu( BN(in' @ W + bias; gamma,beta) [+ res] ), in' = relu(BN(in)) if g_in
__global__ void k_mlpcol(const float* __restrict__ in, const float* __restrict__ W,
                         const float* __restrict__ bias,
                         const float* __restrict__ gamma, const float* __restrict__ beta,
                         const float* __restrict__ res,
                         const float* __restrict__ g_in, const float* __restrict__ be_in,
                         float* __restrict__ outp) {
    __shared__ float A[64 * 129];
    __shared__ float part[4 * 64];
    int t = threadIdx.x;  // 256
    int j = blockIdx.x;   // 128

    for (int i = t; i < 8192; i += 256) A[(i >> 7) * 129 + (i & 127)] = in[i];
    __syncthreads();

    if (g_in) {
        if (t < 128) {
            int c = t;
            float mu = 0.f;
            for (int r = 0; r < 64; r++) mu += A[r * 129 + c];
            mu *= (1.f / 64.f);
            float var = 0.f;
            for (int r = 0; r < 64; r++) { float d = A[r * 129 + c] - mu; var += d * d; }
            var *= (1.f / 64.f);
            float sc = rsqrtf(var + 1e-5f) * g_in[c], sh = be_in[c];
            for (int r = 0; r < 64; r++) {
                float v = (A[r * 129 + c] - mu) * sc + sh;
                A[r * 129 + c] = v > 0.f ? v : 0.f;
            }
        }
        __syncthreads();
    }

    int r = t & 63, q = t >> 6;
    float acc = 0.f;
    int k0 = q * 32;
    #pragma unroll
    for (int k = 0; k < 32; k++) acc += A[r * 129 + k0 + k] * W[(k0 + k) * 128 + j];
    part[q * 64 + r] = acc;
    __syncthreads();

    if (t < 64) {
        float v = part[t] + part[64 + t] + part[128 + t] + part[192 + t] + bias[j];
        float mu = wave_sum(v) * (1.f / 64.f);
        float d = v - mu;
        float var = wave_sum(d * d) * (1.f / 64.f);
        float o = d * rsqrtf(var + 1e-5f) * gamma[j] + beta[j];
        if (res) o += res[t * 128 + j];
        outp[t * 128 + j] = o > 0.f ? o : 0.f;
    }
}

__global__ void k_out(const float* __restrict__ z4, const float* __restrict__ W_out,
                      const float* b_out, float* __restrict__ out) {
    int g = threadIdx.x;  // 64
    float acc = b_out[0];
    for (int j = 0; j < 128; j++) acc += z4[g * 128 + j] * W_out[j];
    out[g] = acc;
}

extern "C" void kernel_launch(void* const* d_in, const int* in_sizes, int n_in,
                              void* d_out, int out_size, void* d_ws, size_t ws_size,
                              hipStream_t stream) {
    const float* x      = (const float*)d_in[0];
    const int*   ei     = (const int*)d_in[1];
    const float* ea     = (const float*)d_in[2];
    const int*   batch  = (const int*)d_in[3];
    const float* W_edge = (const float*)d_in[4];
    const float* b_edge = (const float*)d_in[5];
    const float* W_pre  = (const float*)d_in[6];
    const float* b_pre  = (const float*)d_in[7];
    const float* W_post = (const float*)d_in[8];
    const float* b_post = (const float*)d_in[9];
    const float* W_lin  = (const float*)d_in[10];
    const float* b_lin  = (const float*)d_in[11];
    const float* g1     = (const float*)d_in[12];
    const float* be1    = (const float*)d_in[13];
    const float* W2     = (const float*)d_in[14];
    const float* b2     = (const float*)d_in[15];
    const float* g2     = (const float*)d_in[16];
    const float* be2    = (const float*)d_in[17];
    const float* Wr1    = (const float*)d_in[18];
    const float* br1    = (const float*)d_in[19];
    const float* gr1    = (const float*)d_in[20];
    const float* ber1   = (const float*)d_in[21];
    const float* Wr2    = (const float*)d_in[22];
    const float* br2    = (const float*)d_in[23];
    const float* gr2    = (const float*)d_in[24];
    const float* ber2   = (const float*)d_in[25];
    const float* W_out  = (const float*)d_in[26];
    const float* b_out  = (const float*)d_in[27];
    float* out = (float*)d_out;

    const int N = in_sizes[0] / F;      // 50000  (must be <= 65536 for record packing)
    const int E = in_sizes[1] / 2;      // 800000
    const int G = out_size;             // 64
    const int NB = (N + 63) >> 6;       // 782 buckets

    char* p = (char*)d_ws;
    auto alloc = [&](size_t nbytes) { void* r = p; p += (nbytes + 255) & ~(size_t)255; return r; };
    bf16*  AB     = (bf16*)alloc((size_t)N * 128 * sizeof(bf16));
    bf16*  agg    = (bf16*)alloc((size_t)N * 256 * sizeof(bf16));
    float* ampv   = (float*)alloc((size_t)N * sizeof(float));
    int*   gcur   = (int*)alloc((size_t)NB * sizeof(int));
    int2*  gout   = (int2*)alloc((size_t)NB * BCAP * sizeof(int2));
    float* uc     = (float*)alloc(128 * sizeof(float));
    float* gfeat  = (float*)alloc((size_t)G * 832 * sizeof(float));
    int*   gcnt   = (int*)alloc((size_t)G * sizeof(int));
    float* Zin    = (float*)alloc(64 * 128 * sizeof(float));
    float* z2b    = (float*)alloc(64 * 128 * sizeof(float));
    float* z3b    = (float*)alloc(64 * 128 * sizeof(float));
    float* z4b    = (float*)alloc(64 * 128 * sizeof(float));

    const int GF = G * 832;
    int initb = (GF + 255) / 256;
    if ((NB + 255) / 256 > initb) initb = (NB + 255) / 256;
    const int GRB = 512;
    const int GRCH = (N + GRB - 1) / GRB;
    const int ABB = ((N + 15) / 16 + 3) / 4;
    const int NBT = (E + BTILE - 1) / BTILE;

    k_init<<<initb + 1, 256, 0, stream>>>(gcur, gfeat, gcnt, NB, GF, G,
                                          W_edge, b_edge, W_pre, b_pre, uc);
    k_ab_mfma<<<ABB, 256, 0, stream>>>(x, W_pre, AB, N);
    k_bucket<<<NBT, 256, 0, stream>>>(ei, ea, gcur, gout, E, NB);
    k_edge<<<NB, 256, 0, stream>>>(AB, gout, gcur, uc, agg, ampv, N);
    k_greduce2<<<GRB, 256, 0, stream>>>(x, agg, ampv, batch, gfeat, gcnt, N, GRCH);
    k_post1<<<G, 128, 0, stream>>>(gfeat, gcnt, W_post, b_post, W_lin, b_lin, Zin);
    k_mlpcol<<<HG, 256, 0, stream>>>(Zin, W2, b2, g2, be2, nullptr, g1, be1, z2b);
    k_mlpcol<<<HL, 256, 0, stream>>>(z2b, Wr1, br1, gr1, ber1, nullptr, nullptr, nullptr, z3b);
    k_mlpcol<<<HL, 256, 0, stream>>>(z3b, Wr2, br2, gr2, ber2, z2b, nullptr, nullptr, z4b);
    k_out<<<1, 64, 0, stream>>>(z4b, W_out, b_out, out);
}

// Round 8
// 261.513 us; speedup vs baseline: 1.9588x; 1.1356x over previous
//
#include <hip/hip_runtime.h>
#include <hip/hip_bf16.h>

using bf16 = __hip_bfloat16;

#define F 64
#define HG 128
#define HL 128
#define AVG_LOG_INV 0.45511961331341866f  // 1/log(9)
#define BSH 5            // 32 nodes per bucket
#define BNODES 32
#define BCAP 1024        // per-bucket record capacity (mean 512, +22 sigma)
#define BTILE 8192       // edges per k_bucket block
#define NBMAX 1664       // LDS hist array size (>= NB)

typedef short short8 __attribute__((ext_vector_type(8)));
typedef float floatx4 __attribute__((ext_vector_type(4)));

__device__ __forceinline__ float b2f(bf16 v) { return __bfloat162float(v); }
__device__ __forceinline__ bf16 f2b(float v) { return __float2bfloat16(v); }
__device__ __forceinline__ short f2bs(float v) { bf16 h = f2b(v); return *(short*)&h; }

__device__ __forceinline__ unsigned packbf2(float x, float y) {
    bf16 a = f2b(x), b = f2b(y);
    unsigned short ua = *(unsigned short*)&a, ub = *(unsigned short*)&b;
    return ((unsigned)ub << 16) | (unsigned)ua;
}

__device__ __forceinline__ float wave_sum(float v) {
    #pragma unroll
    for (int m = 32; m > 0; m >>= 1) v += __shfl_xor(v, m);
    return v;
}

// fused: zero gcur/gfeat/gcnt + compute uc[128] in the last block
__global__ void k_init(int* __restrict__ gcur, float* __restrict__ gfeat,
                       int* __restrict__ gcnt, int NB, int GF, int G,
                       const float* __restrict__ W_edge, const float* __restrict__ b_edge,
                       const float* __restrict__ W_pre, const float* __restrict__ b_pre,
                       float* __restrict__ uc) {
    if (blockIdx.x == gridDim.x - 1) {
        int f = threadIdx.x;
        if (f < 64) {
            float u = 0.f, c = b_pre[f];
            for (int k = 0; k < 64; k++) {
                float w3 = W_pre[(128 + k) * 64 + f];
                u += W_edge[k] * w3;
                c += b_edge[k] * w3;
            }
            uc[f] = u; uc[64 + f] = c;
        } else if (f - 64 < G) {
            gcnt[f - 64] = 0;
        }
        return;
    }
    int i = blockIdx.x * 256 + threadIdx.x;
    if (i < NB) gcur[i] = 0;
    if (i < GF) gfeat[i] = 0.f;
}

// MFMA AB staging: AB[n][0:64] = x[n]@W1, AB[n][64:128] = x[n]@W2  (bf16)
__global__ void k_ab_mfma(const float* __restrict__ x, const float* __restrict__ W_pre,
                          bf16* __restrict__ AB, int N) {
    __shared__ unsigned short wt[128 * 72];  // wt[m][k]
    for (int idx = threadIdx.x; idx < 8192; idx += 256) {
        int k = idx >> 7, m = idx & 127;
        float v = W_pre[((m & 64) + k) * 64 + (m & 63)];
        wt[m * 72 + k] = (unsigned short)f2bs(v);
    }
    __syncthreads();

    int lane = threadIdx.x & 63;
    int row = lane & 15, quad = lane >> 4;
    int w = (blockIdx.x * blockDim.x + threadIdx.x) >> 6;
    int nwaves = (gridDim.x * blockDim.x) >> 6;
    int ntiles = (N + 15) >> 4;

    for (int tile = w; tile < ntiles; tile += nwaves) {
        int m0 = tile << 4;
        int node_a = m0 + row; if (node_a >= N) node_a = N - 1;
        short8 a[2];
        #pragma unroll
        for (int h = 0; h < 2; h++) {
            const float* xp = x + (size_t)node_a * 64 + h * 32 + quad * 8;
            floatx4 v0 = *(const floatx4*)xp;
            floatx4 v1 = *(const floatx4*)(xp + 4);
            #pragma unroll
            for (int j = 0; j < 4; j++) { a[h][j] = f2bs(v0[j]); a[h][4 + j] = f2bs(v1[j]); }
        }
        #pragma unroll
        for (int t = 0; t < 8; t++) {
            int fbase = t * 16;
            floatx4 c = {0.f, 0.f, 0.f, 0.f};
            #pragma unroll
            for (int h = 0; h < 2; h++) {
                short8 b = *(const short8*)(wt + (fbase + row) * 72 + h * 32 + quad * 8);
                c = __builtin_amdgcn_mfma_f32_16x16x32_bf16(a[h], b, c, 0, 0, 0);
            }
            #pragma unroll
            for (int r = 0; r < 4; r++) {
                int node = m0 + quad * 4 + r;
                if (node < N) AB[(size_t)node * 128 + fbase + row] = f2b(c[r]);
            }
        }
    }
}

// bucket partition: bucket = dst>>5 (32 nodes/bucket). LDS-aggregated cursor
// reservations; records land in hot per-bucket L2 ranges -> writes merge.
// rec = ((dst<<16)|src, ea_f32bits). REQUIRES N <= 65536.
__global__ void k_bucket(const int* __restrict__ ei, const float* __restrict__ ea,
                         int* __restrict__ gcur, int2* __restrict__ gout,
                         int E, int NB) {
    __shared__ int2 recs[BTILE];
    __shared__ int hist[NBMAX], gst[NBMAX], lrk[NBMAX];
    int t = threadIdx.x;
    for (int b = t; b < NB; b += 256) hist[b] = 0;
    __syncthreads();
    int base = blockIdx.x * BTILE;
    int lim = E - base; if (lim > BTILE) lim = BTILE;
    for (int i = t; i < lim; i += 256) {
        int e = base + i;
        int src = ei[e], dst = ei[E + e];
        recs[i] = make_int2((dst << 16) | src, __float_as_int(ea[e]));
        atomicAdd(&hist[dst >> BSH], 1);
    }
    __syncthreads();
    for (int b = t; b < NB; b += 256) {
        int h = hist[b];
        lrk[b] = 0;
        gst[b] = (h > 0) ? atomicAdd(&gcur[b], h) : 0;
    }
    __syncthreads();
    for (int i = t; i < lim; i += 256) {
        int2 r = recs[i];
        int b = ((unsigned)r.x) >> (16 + BSH);
        int k = atomicAdd(&lrk[b], 1);
        int pos = gst[b] + k;
        if (pos < BCAP) gout[(size_t)b * BCAP + pos] = r;
    }
}

// one block per bucket (32 nodes): LDS counting-sort records by node, then
// per-node reduction (wave per node; lanes = feature pairs, 2 edges/iter)
__global__ void k_edge(const bf16* __restrict__ AB, const int2* __restrict__ gout,
                       const int* __restrict__ gcur, const float* __restrict__ uc,
                       bf16* __restrict__ agg, float* __restrict__ ampv, int N) {
    __shared__ int2 recs[BCAP], sortd[BCAP];
    __shared__ int ncnt[BNODES], nofs[BNODES], nrank[BNODES];
    int t = threadIdx.x;
    int b = blockIdx.x;
    int nn = N - b * BNODES; if (nn > BNODES) nn = BNODES;
    int ecnt = gcur[b]; if (ecnt > BCAP) ecnt = BCAP;

    for (int i = t; i < ecnt; i += 256) recs[i] = gout[(size_t)b * BCAP + i];
    if (t < BNODES) { ncnt[t] = 0; nrank[t] = 0; }
    __syncthreads();
    for (int i = t; i < ecnt; i += 256)
        atomicAdd(&ncnt[((unsigned)recs[i].x >> 16) & (BNODES - 1)], 1);
    __syncthreads();
    if (t < BNODES) {  // exclusive scan over node counts (first 32 lanes of wave 0)
        int v = ncnt[t], inc = v;
        #pragma unroll
        for (int m = 1; m < BNODES; m <<= 1) { int u = __shfl_up(inc, m); if (t >= m) inc += u; }
        nofs[t] = inc - v;
    }
    __syncthreads();
    for (int i = t; i < ecnt; i += 256) {
        int2 r = recs[i];
        int nl = ((unsigned)r.x >> 16) & (BNODES - 1);
        int k = atomicAdd(&nrank[nl], 1);
        sortd[nofs[nl] + k] = r;
    }
    __syncthreads();

    int lane = t & 63, w = t >> 6;
    int half = lane & 31, hi32 = lane >> 5;
    float2 u2 = *(const float2*)(uc + 2 * half);
    float2 c2 = *(const float2*)(uc + 64 + 2 * half);

    for (int nl = w; nl < nn; nl += 4) {
        int n = b * BNODES + nl;
        int lo = nofs[nl], cnt = ncnt[nl], hi = lo + cnt;

        unsigned apack = *(const unsigned*)(AB + (size_t)n * 128 + 2 * half);
        float acx = __uint_as_float(apack << 16) + c2.x;
        float acy = __uint_as_float(apack & 0xffff0000u) + c2.y;

        float sx = 0.f, sy = 0.f, qx = 0.f, qy = 0.f;
        float mnx = 3.4e38f, mny = 3.4e38f, mxx = -3.4e38f, mxy = -3.4e38f;

        for (int base = lo; base < hi; base += 64) {
            int nb = hi - base; if (nb > 64) nb = 64;
            int2 rec = (lane < nb) ? sortd[base + lane] : make_int2(0, 0);
            int vsn = rec.x & 0xFFFF;
            float vea = __int_as_float(rec.y);
            int full = nb & ~1;
            for (int i = 0; i < full; i += 2) {
                int   sn = __shfl(vsn, i + hi32);
                float eav = __shfl(vea, i + hi32);
                unsigned bp = *(const unsigned*)(AB + (size_t)sn * 128 + 64 + 2 * half);
                float bx = __uint_as_float(bp << 16);
                float by = __uint_as_float(bp & 0xffff0000u);
                float m0 = fmaf(eav, u2.x, acx) + bx;
                float m1 = fmaf(eav, u2.y, acy) + by;
                sx += m0; qx = fmaf(m0, m0, qx);
                sy += m1; qy = fmaf(m1, m1, qy);
                mnx = fminf(mnx, m0); mxx = fmaxf(mxx, m0);
                mny = fminf(mny, m1); mxy = fmaxf(mxy, m1);
            }
            if (nb & 1) {
                int   sn = __shfl(vsn, full);
                float eav = __shfl(vea, full);
                unsigned bp = *(const unsigned*)(AB + (size_t)sn * 128 + 64 + 2 * half);
                float bx = __uint_as_float(bp << 16);
                float by = __uint_as_float(bp & 0xffff0000u);
                float m0 = fmaf(eav, u2.x, acx) + bx;
                float m1 = fmaf(eav, u2.y, acy) + by;
                if (hi32 == 0) {
                    sx += m0; qx = fmaf(m0, m0, qx);
                    sy += m1; qy = fmaf(m1, m1, qy);
                    mnx = fminf(mnx, m0); mxx = fmaxf(mxx, m0);
                    mny = fminf(mny, m1); mxy = fmaxf(mxy, m1);
                }
            }
        }
        sx += __shfl_xor(sx, 32); sy += __shfl_xor(sy, 32);
        qx += __shfl_xor(qx, 32); qy += __shfl_xor(qy, 32);
        mnx = fminf(mnx, __shfl_xor(mnx, 32)); mny = fminf(mny, __shfl_xor(mny, 32));
        mxx = fmaxf(mxx, __shfl_xor(mxx, 32)); mxy = fmaxf(mxy, __shfl_xor(mxy, 32));

        float c1 = (cnt > 0) ? (float)cnt : 1.f;
        float inv = 1.f / c1;
        float mex = sx * inv, mey = sy * inv;
        float vx = qx * inv - mex * mex; if (vx < 0.f) vx = 0.f;
        float vy = qy * inv - mey * mey; if (vy < 0.f) vy = 0.f;
        float sdx = sqrtf(vx + 1e-5f), sdy = sqrtf(vy + 1e-5f);
        if (cnt == 0) { mnx = mny = mxx = mxy = 0.f; }

        size_t ob = (size_t)n * 256 + 2 * half;
        if (hi32 == 0) {
            *(unsigned*)(agg + ob)       = packbf2(mex, mey);
            *(unsigned*)(agg + ob + 64)  = packbf2(mnx, mny);
        } else {
            *(unsigned*)(agg + ob + 128) = packbf2(mxx, mxy);
            *(unsigned*)(agg + ob + 192) = packbf2(sdx, sdy);
        }
        if (lane == 0) ampv[n] = logf(c1 + 1.f) * AVG_LOG_INV;
    }
}

// chunked per-graph SUM of 832-dim feature vector [x | agg | agg*amp | agg/amp]
__global__ void k_greduce2(const float* __restrict__ x, const bf16* __restrict__ agg,
                           const float* __restrict__ ampv, const int* __restrict__ batch,
                           float* __restrict__ gfeat, int* __restrict__ gcnt,
                           int N, int chunk) {
    int t = threadIdx.x;  // 256
    int lo = blockIdx.x * chunk;
    int hi = lo + chunk; if (hi > N) hi = N;
    if (lo >= hi) return;
    int curg = batch[lo];
    float s1 = 0.f, s2 = 0.f, s3 = 0.f, sx = 0.f;
    int cnt = 0;
    for (int n = lo; n < hi; n++) {
        int g = batch[n];
        if (g != curg) {
            float* gf = gfeat + (size_t)curg * 832;
            atomicAdd(&gf[64 + t], s1);
            atomicAdd(&gf[320 + t], s2);
            atomicAdd(&gf[576 + t], s3);
            if (t < 64) atomicAdd(&gf[t], sx);
            if (t == 0) atomicAdd(&gcnt[curg], cnt);
            s1 = s2 = s3 = sx = 0.f; cnt = 0; curg = g;
        }
        float amp = ampv[n];
        float av = b2f(agg[(size_t)n * 256 + t]);
        s1 += av; s2 += av * amp; s3 += av / amp;
        if (t < 64) sx += x[(size_t)n * 64 + t];
        cnt++;
    }
    float* gf = gfeat + (size_t)curg * 832;
    atomicAdd(&gf[64 + t], s1);
    atomicAdd(&gf[320 + t], s2);
    atomicAdd(&gf[576 + t], s3);
    if (t < 64) atomicAdd(&gf[t], sx);
    if (t == 0) atomicAdd(&gcnt[curg], cnt);
}

// Zin[g] = ((gfeat[g]/cnt) @ W_post + b_post) @ W_lin + b_lin ; zero if empty graph
__global__ void k_post1(const float* __restrict__ gfeat, const int* __restrict__ gcnt,
                        const float* __restrict__ W_post, const float* __restrict__ b_post,
                        const float* __restrict__ W_lin, const float* __restrict__ b_lin,
                        float* __restrict__ Zin) {
    int g = blockIdx.x, j = threadIdx.x;  // 128
    __shared__ float feat[832];
    __shared__ float z1[128];
    int cg = gcnt[g];
    float r = 1.f / ((cg > 0) ? (float)cg : 1.f);
    for (int i = j; i < 832; i += 128) feat[i] = gfeat[(size_t)g * 832 + i] * r;
    __syncthreads();
    float acc = b_post[j];
    for (int k = 0; k < 832; k++) acc += feat[k] * W_post[k * 128 + j];
    z1[j] = acc;
    __syncthreads();
    float a2 = b_lin[j];
    for (int k = 0; k < 128; k++) a2 += z1[k] * W_lin[k * 128 + j];
    if (cg == 0) a2 = 0.f;
    Zin[g * 128 + j] = a2;
}

// column-parallel MLP layer: block j computes output column j of
//   out = relu( BN(in' @ W + bias; gamma,beta) [+ res] ), in' = relu(BN(in)) if g_in
__global__ void k_mlpcol(const float* __restrict__ in, const float* __restrict__ W,
                         const float* __restrict__ bias,
                         const float* __restrict__ gamma, const float* __restrict__ beta,
                         const float* __restrict__ res,
                         const float* __restrict__ g_in, const float* __restrict__ be_in,
                         float* __restrict__ outp) {
    __shared__ float A[64 * 129];
    __shared__ float part[4 * 64];
    int t = threadIdx.x;  // 256
    int j = blockIdx.x;   // 128

    for (int i = t; i < 8192; i += 256) A[(i >> 7) * 129 + (i & 127)] = in[i];
    __syncthreads();

    if (g_in) {
        if (t < 128) {
            int c = t;
            float mu = 0.f;
            for (int r = 0; r < 64; r++) mu += A[r * 129 + c];
            mu *= (1.f / 64.f);
            float var = 0.f;
            for (int r = 0; r < 64; r++) { float d = A[r * 129 + c] - mu; var += d * d; }
            var *= (1.f / 64.f);
            float sc = rsqrtf(var + 1e-5f) * g_in[c], sh = be_in[c];
            for (int r = 0; r < 64; r++) {
                float v = (A[r * 129 + c] - mu) * sc + sh;
                A[r * 129 + c] = v > 0.f ? v : 0.f;
            }
        }
        __syncthreads();
    }

    int r = t & 63, q = t >> 6;
    float acc = 0.f;
    int k0 = q * 32;
    #pragma unroll
    for (int k = 0; k < 32; k++) acc += A[r * 129 + k0 + k] * W[(k0 + k) * 128 + j];
    part[q * 64 + r] = acc;
    __syncthreads();

    if (t < 64) {
        float v = part[t] + part[64 + t] + part[128 + t] + part[192 + t] + bias[j];
        float mu = wave_sum(v) * (1.f / 64.f);
        float d = v - mu;
        float var = wave_sum(d * d) * (1.f / 64.f);
        float o = d * rsqrtf(var + 1e-5f) * gamma[j] + beta[j];
        if (res) o += res[t * 128 + j];
        outp[t * 128 + j] = o > 0.f ? o : 0.f;
    }
}

__global__ void k_out(const float* __restrict__ z4, const float* __restrict__ W_out,
                      const float* b_out, float* __restrict__ out) {
    int g = threadIdx.x;  // 64
    float acc = b_out[0];
    for (int j = 0; j < 128; j++) acc += z4[g * 128 + j] * W_out[j];
    out[g] = acc;
}

extern "C" void kernel_launch(void* const* d_in, const int* in_sizes, int n_in,
                              void* d_out, int out_size, void* d_ws, size_t ws_size,
                              hipStream_t stream) {
    const float* x      = (const float*)d_in[0];
    const int*   ei     = (const int*)d_in[1];
    const float* ea     = (const float*)d_in[2];
    const int*   batch  = (const int*)d_in[3];
    const float* W_edge = (const float*)d_in[4];
    const float* b_edge = (const float*)d_in[5];
    const float* W_pre  = (const float*)d_in[6];
    const float* b_pre  = (const float*)d_in[7];
    const float* W_post = (const float*)d_in[8];
    const float* b_post = (const float*)d_in[9];
    const float* W_lin  = (const float*)d_in[10];
    const float* b_lin  = (const float*)d_in[11];
    const float* g1     = (const float*)d_in[12];
    const float* be1    = (const float*)d_in[13];
    const float* W2     = (const float*)d_in[14];
    const float* b2     = (const float*)d_in[15];
    const float* g2     = (const float*)d_in[16];
    const float* be2    = (const float*)d_in[17];
    const float* Wr1    = (const float*)d_in[18];
    const float* br1    = (const float*)d_in[19];
    const float* gr1    = (const float*)d_in[20];
    const float* ber1   = (const float*)d_in[21];
    const float* Wr2    = (const float*)d_in[22];
    const float* br2    = (const float*)d_in[23];
    const float* gr2    = (const float*)d_in[24];
    const float* ber2   = (const float*)d_in[25];
    const float* W_out  = (const float*)d_in[26];
    const float* b_out  = (const float*)d_in[27];
    float* out = (float*)d_out;

    const int N = in_sizes[0] / F;      // 50000  (must be <= 65536 for record packing)
    const int E = in_sizes[1] / 2;      // 800000
    const int G = out_size;             // 64
    const int NB = (N + BNODES - 1) >> BSH;  // 1563 buckets

    char* p = (char*)d_ws;
    auto alloc = [&](size_t nbytes) { void* r = p; p += (nbytes + 255) & ~(size_t)255; return r; };
    bf16*  AB     = (bf16*)alloc((size_t)N * 128 * sizeof(bf16));
    bf16*  agg    = (bf16*)alloc((size_t)N * 256 * sizeof(bf16));
    float* ampv   = (float*)alloc((size_t)N * sizeof(float));
    int*   gcur   = (int*)alloc((size_t)NB * sizeof(int));
    int2*  gout   = (int2*)alloc((size_t)NB * BCAP * sizeof(int2));
    float* uc     = (float*)alloc(128 * sizeof(float));
    float* gfeat  = (float*)alloc((size_t)G * 832 * sizeof(float));
    int*   gcnt   = (int*)alloc((size_t)G * sizeof(int));
    float* Zin    = (float*)alloc(64 * 128 * sizeof(float));
    float* z2b    = (float*)alloc(64 * 128 * sizeof(float));
    float* z3b    = (float*)alloc(64 * 128 * sizeof(float));
    float* z4b    = (float*)alloc(64 * 128 * sizeof(float));

    const int GF = G * 832;
    int initb = (GF + 255) / 256;
    if ((NB + 255) / 256 > initb) initb = (NB + 255) / 256;
    const int GRB = 1024;
    const int GRCH = (N + GRB - 1) / GRB;
    const int ABB = ((N + 15) / 16 + 3) / 4;
    const int NBT = (E + BTILE - 1) / BTILE;

    k_init<<<initb + 1, 256, 0, stream>>>(gcur, gfeat, gcnt, NB, GF, G,
                                          W_edge, b_edge, W_pre, b_pre, uc);
    k_ab_mfma<<<ABB, 256, 0, stream>>>(x, W_pre, AB, N);
    k_bucket<<<NBT, 256, 0, stream>>>(ei, ea, gcur, gout, E, NB);
    k_edge<<<NB, 256, 0, stream>>>(AB, gout, gcur, uc, agg, ampv, N);
    k_greduce2<<<GRB, 256, 0, stream>>>(x, agg, ampv, batch, gfeat, gcnt, N, GRCH);
    k_post1<<<G, 128, 0, stream>>>(gfeat, gcnt, W_post, b_post, W_lin, b_lin, Zin);
    k_mlpcol<<<HG, 256, 0, stream>>>(Zin, W2, b2, g2, be2, nullptr, g1, be1, z2b);
    k_mlpcol<<<HL, 256, 0, stream>>>(z2b, Wr1, br1, gr1, ber1, nullptr, nullptr, nullptr, z3b);
    k_mlpcol<<<HL, 256, 0, stream>>>(z3b, Wr2, br2, gr2, ber2, z2b, nullptr, nullptr, z4b);
    k_out<<<1, 64, 0, stream>>>(z4b, W_out, b_out, out);
}

// Round 9
// 240.312 us; speedup vs baseline: 2.1316x; 1.0882x over previous
//
#include <hip/hip_runtime.h>
#include <hip/hip_bf16.h>

using bf16 = __hip_bfloat16;

#define F 64
#define HG 128
#define HL 128
#define AVG_LOG_INV 0.45511961331341866f  // 1/log(9)
#define BSH 5            // 32 nodes per bucket
#define BNODES 32
#define BCAP 1024        // per-bucket record capacity (mean 512, +22 sigma)
#define BTILE 8192       // edges per k_bucket block
#define NBMAX 1664       // LDS hist array size (>= NB)

typedef short short8 __attribute__((ext_vector_type(8)));
typedef float floatx4 __attribute__((ext_vector_type(4)));

__device__ __forceinline__ float b2f(bf16 v) { return __bfloat162float(v); }
__device__ __forceinline__ bf16 f2b(float v) { return __float2bfloat16(v); }
__device__ __forceinline__ short f2bs(float v) { bf16 h = f2b(v); return *(short*)&h; }

__device__ __forceinline__ unsigned packbf2(float x, float y) {
    bf16 a = f2b(x), b = f2b(y);
    unsigned short ua = *(unsigned short*)&a, ub = *(unsigned short*)&b;
    return ((unsigned)ub << 16) | (unsigned)ua;
}

__device__ __forceinline__ float wave_sum(float v) {
    #pragma unroll
    for (int m = 32; m > 0; m >>= 1) v += __shfl_xor(v, m);
    return v;
}

// fused: zero gcur/gfeat/gcnt + compute uc[128] in the last block
__global__ void k_init(int* __restrict__ gcur, float* __restrict__ gfeat,
                       int* __restrict__ gcnt, int NB, int GF, int G,
                       const float* __restrict__ W_edge, const float* __restrict__ b_edge,
                       const float* __restrict__ W_pre, const float* __restrict__ b_pre,
                       float* __restrict__ uc) {
    if (blockIdx.x == gridDim.x - 1) {
        int f = threadIdx.x;
        if (f < 64) {
            float u = 0.f, c = b_pre[f];
            for (int k = 0; k < 64; k++) {
                float w3 = W_pre[(128 + k) * 64 + f];
                u += W_edge[k] * w3;
                c += b_edge[k] * w3;
            }
            uc[f] = u; uc[64 + f] = c;
        } else if (f - 64 < G) {
            gcnt[f - 64] = 0;
        }
        return;
    }
    int i = blockIdx.x * 256 + threadIdx.x;
    if (i < NB) gcur[i] = 0;
    if (i < GF) gfeat[i] = 0.f;
}

// MFMA AB staging: AB[n][0:64] = x[n]@W1, AB[n][64:128] = x[n]@W2  (bf16)
__global__ void k_ab_mfma(const float* __restrict__ x, const float* __restrict__ W_pre,
                          bf16* __restrict__ AB, int N) {
    __shared__ unsigned short wt[128 * 72];  // wt[m][k]
    for (int idx = threadIdx.x; idx < 8192; idx += 256) {
        int k = idx >> 7, m = idx & 127;
        float v = W_pre[((m & 64) + k) * 64 + (m & 63)];
        wt[m * 72 + k] = (unsigned short)f2bs(v);
    }
    __syncthreads();

    int lane = threadIdx.x & 63;
    int row = lane & 15, quad = lane >> 4;
    int w = (blockIdx.x * blockDim.x + threadIdx.x) >> 6;
    int nwaves = (gridDim.x * blockDim.x) >> 6;
    int ntiles = (N + 15) >> 4;

    for (int tile = w; tile < ntiles; tile += nwaves) {
        int m0 = tile << 4;
        int node_a = m0 + row; if (node_a >= N) node_a = N - 1;
        short8 a[2];
        #pragma unroll
        for (int h = 0; h < 2; h++) {
            const float* xp = x + (size_t)node_a * 64 + h * 32 + quad * 8;
            floatx4 v0 = *(const floatx4*)xp;
            floatx4 v1 = *(const floatx4*)(xp + 4);
            #pragma unroll
            for (int j = 0; j < 4; j++) { a[h][j] = f2bs(v0[j]); a[h][4 + j] = f2bs(v1[j]); }
        }
        #pragma unroll
        for (int t = 0; t < 8; t++) {
            int fbase = t * 16;
            floatx4 c = {0.f, 0.f, 0.f, 0.f};
            #pragma unroll
            for (int h = 0; h < 2; h++) {
                short8 b = *(const short8*)(wt + (fbase + row) * 72 + h * 32 + quad * 8);
                c = __builtin_amdgcn_mfma_f32_16x16x32_bf16(a[h], b, c, 0, 0, 0);
            }
            #pragma unroll
            for (int r = 0; r < 4; r++) {
                int node = m0 + quad * 4 + r;
                if (node < N) AB[(size_t)node * 128 + fbase + row] = f2b(c[r]);
            }
        }
    }
}

// bucket partition: bucket = dst>>5 (32 nodes/bucket). LDS-aggregated cursor
// reservations; records land in hot per-bucket L2 ranges -> writes merge.
// rec = ((dst<<16)|src, ea_f32bits). REQUIRES N <= 65536. 1024 threads.
__global__ void k_bucket(const int* __restrict__ ei, const float* __restrict__ ea,
                         int* __restrict__ gcur, int2* __restrict__ gout,
                         int E, int NB) {
    __shared__ int2 recs[BTILE];
    __shared__ int hist[NBMAX], gst[NBMAX], lrk[NBMAX];
    int t = threadIdx.x;  // 1024
    for (int b = t; b < NB; b += 1024) hist[b] = 0;
    __syncthreads();
    int base = blockIdx.x * BTILE;
    int lim = E - base; if (lim > BTILE) lim = BTILE;
    for (int i = t; i < lim; i += 1024) {
        int e = base + i;
        int src = ei[e], dst = ei[E + e];
        recs[i] = make_int2((dst << 16) | src, __float_as_int(ea[e]));
        atomicAdd(&hist[dst >> BSH], 1);
    }
    __syncthreads();
    for (int b = t; b < NB; b += 1024) {
        int h = hist[b];
        lrk[b] = 0;
        gst[b] = (h > 0) ? atomicAdd(&gcur[b], h) : 0;
    }
    __syncthreads();
    for (int i = t; i < lim; i += 1024) {
        int2 r = recs[i];
        int b = ((unsigned)r.x) >> (16 + BSH);
        int k = atomicAdd(&lrk[b], 1);
        int pos = gst[b] + k;
        if (pos < BCAP) gout[(size_t)b * BCAP + pos] = r;
    }
}

// one block (512 thr, 8 waves) per bucket (32 nodes): LDS counting-sort,
// then per-node reduction. Gathers software-pipelined 4-deep.
__global__ void k_edge(const bf16* __restrict__ AB, const int2* __restrict__ gout,
                       const int* __restrict__ gcur, const float* __restrict__ uc,
                       bf16* __restrict__ agg, float* __restrict__ ampv, int N) {
    __shared__ int2 recs[BCAP], sortd[BCAP];
    __shared__ int ncnt[BNODES], nofs[BNODES], nrank[BNODES];
    int t = threadIdx.x;  // 512
    int b = blockIdx.x;
    int nn = N - b * BNODES; if (nn > BNODES) nn = BNODES;
    int ecnt = gcur[b]; if (ecnt > BCAP) ecnt = BCAP;

    for (int i = t; i < ecnt; i += 512) recs[i] = gout[(size_t)b * BCAP + i];
    if (t < BNODES) { ncnt[t] = 0; nrank[t] = 0; }
    __syncthreads();
    for (int i = t; i < ecnt; i += 512)
        atomicAdd(&ncnt[((unsigned)recs[i].x >> 16) & (BNODES - 1)], 1);
    __syncthreads();
    if (t < BNODES) {  // exclusive scan over node counts (first 32 lanes of wave 0)
        int v = ncnt[t], inc = v;
        #pragma unroll
        for (int m = 1; m < BNODES; m <<= 1) { int u = __shfl_up(inc, m); if (t >= m) inc += u; }
        nofs[t] = inc - v;
    }
    __syncthreads();
    for (int i = t; i < ecnt; i += 512) {
        int2 r = recs[i];
        int nl = ((unsigned)r.x >> 16) & (BNODES - 1);
        int k = atomicAdd(&nrank[nl], 1);
        sortd[nofs[nl] + k] = r;
    }
    __syncthreads();

    int lane = t & 63, w = t >> 6;  // 8 waves
    int half = lane & 31, hi32 = lane >> 5;
    float2 u2 = *(const float2*)(uc + 2 * half);
    float2 c2 = *(const float2*)(uc + 64 + 2 * half);

    for (int nl = w; nl < nn; nl += 8) {
        int n = b * BNODES + nl;
        int lo = nofs[nl], cnt = ncnt[nl], hi = lo + cnt;

        unsigned apack = *(const unsigned*)(AB + (size_t)n * 128 + 2 * half);
        float acx = __uint_as_float(apack << 16) + c2.x;
        float acy = __uint_as_float(apack & 0xffff0000u) + c2.y;

        float sx = 0.f, sy = 0.f, qx = 0.f, qy = 0.f;
        float mnx = 3.4e38f, mny = 3.4e38f, mxx = -3.4e38f, mxy = -3.4e38f;

        auto acc2 = [&](unsigned bp, float eav) {
            float bx = __uint_as_float(bp << 16);
            float by = __uint_as_float(bp & 0xffff0000u);
            float m0 = fmaf(eav, u2.x, acx) + bx;
            float m1 = fmaf(eav, u2.y, acy) + by;
            sx += m0; qx = fmaf(m0, m0, qx);
            sy += m1; qy = fmaf(m1, m1, qy);
            mnx = fminf(mnx, m0); mxx = fmaxf(mxx, m0);
            mny = fminf(mny, m1); mxy = fmaxf(mxy, m1);
        };
        auto gaddr = [&](int sn) {
            return (const unsigned*)(AB + (size_t)sn * 128 + 64 + 2 * half);
        };

        for (int base = lo; base < hi; base += 64) {
            int nb = hi - base; if (nb > 64) nb = 64;
            int2 rec = (lane < nb) ? sortd[base + lane] : make_int2(0, 0);
            int vsn = rec.x & 0xFFFF;
            float vea = __int_as_float(rec.y);
            int i = 0;
            for (; i + 8 <= nb; i += 8) {  // 4 pairs in flight
                int sn0 = __shfl(vsn, i + hi32);
                int sn1 = __shfl(vsn, i + 2 + hi32);
                int sn2 = __shfl(vsn, i + 4 + hi32);
                int sn3 = __shfl(vsn, i + 6 + hi32);
                float e0 = __shfl(vea, i + hi32);
                float e1 = __shfl(vea, i + 2 + hi32);
                float e2 = __shfl(vea, i + 4 + hi32);
                float e3 = __shfl(vea, i + 6 + hi32);
                unsigned b0 = *gaddr(sn0);
                unsigned b1 = *gaddr(sn1);
                unsigned b2 = *gaddr(sn2);
                unsigned b3 = *gaddr(sn3);
                acc2(b0, e0); acc2(b1, e1); acc2(b2, e2); acc2(b3, e3);
            }
            for (; i + 2 <= nb; i += 2) {
                int   sn = __shfl(vsn, i + hi32);
                float ev = __shfl(vea, i + hi32);
                acc2(*gaddr(sn), ev);
            }
            if (i < nb) {  // odd tail: only hi32==0 lanes accumulate
                int   sn = __shfl(vsn, i);
                float ev = __shfl(vea, i);
                unsigned bp = *gaddr(sn);
                if (hi32 == 0) acc2(bp, ev);
            }
        }
        sx += __shfl_xor(sx, 32); sy += __shfl_xor(sy, 32);
        qx += __shfl_xor(qx, 32); qy += __shfl_xor(qy, 32);
        mnx = fminf(mnx, __shfl_xor(mnx, 32)); mny = fminf(mny, __shfl_xor(mny, 32));
        mxx = fmaxf(mxx, __shfl_xor(mxx, 32)); mxy = fmaxf(mxy, __shfl_xor(mxy, 32));

        float c1 = (cnt > 0) ? (float)cnt : 1.f;
        float inv = 1.f / c1;
        float mex = sx * inv, mey = sy * inv;
        float vx = qx * inv - mex * mex; if (vx < 0.f) vx = 0.f;
        float vy = qy * inv - mey * mey; if (vy < 0.f) vy = 0.f;
        float sdx = sqrtf(vx + 1e-5f), sdy = sqrtf(vy + 1e-5f);
        if (cnt == 0) { mnx = mny = mxx = mxy = 0.f; }

        size_t ob = (size_t)n * 256 + 2 * half;
        if (hi32 == 0) {
            *(unsigned*)(agg + ob)       = packbf2(mex, mey);
            *(unsigned*)(agg + ob + 64)  = packbf2(mnx, mny);
        } else {
            *(unsigned*)(agg + ob + 128) = packbf2(mxx, mxy);
            *(unsigned*)(agg + ob + 192) = packbf2(sdx, sdy);
        }
        if (lane == 0) ampv[n] = logf(c1 + 1.f) * AVG_LOG_INV;
    }
}

// chunked per-graph SUM of 832-dim feature vector [x | agg | agg*amp | agg/amp]
__global__ void k_greduce2(const float* __restrict__ x, const bf16* __restrict__ agg,
                           const float* __restrict__ ampv, const int* __restrict__ batch,
                           float* __restrict__ gfeat, int* __restrict__ gcnt,
                           int N, int chunk) {
    int t = threadIdx.x;  // 256
    int lo = blockIdx.x * chunk;
    int hi = lo + chunk; if (hi > N) hi = N;
    if (lo >= hi) return;
    int curg = batch[lo];
    float s1 = 0.f, s2 = 0.f, s3 = 0.f, sx = 0.f;
    int cnt = 0;
    for (int n = lo; n < hi; n++) {
        int g = batch[n];
        if (g != curg) {
            float* gf = gfeat + (size_t)curg * 832;
            atomicAdd(&gf[64 + t], s1);
            atomicAdd(&gf[320 + t], s2);
            atomicAdd(&gf[576 + t], s3);
            if (t < 64) atomicAdd(&gf[t], sx);
            if (t == 0) atomicAdd(&gcnt[curg], cnt);
            s1 = s2 = s3 = sx = 0.f; cnt = 0; curg = g;
        }
        float amp = ampv[n];
        float av = b2f(agg[(size_t)n * 256 + t]);
        s1 += av; s2 += av * amp; s3 += av / amp;
        if (t < 64) sx += x[(size_t)n * 64 + t];
        cnt++;
    }
    float* gf = gfeat + (size_t)curg * 832;
    atomicAdd(&gf[64 + t], s1);
    atomicAdd(&gf[320 + t], s2);
    atomicAdd(&gf[576 + t], s3);
    if (t < 64) atomicAdd(&gf[t], sx);
    if (t == 0) atomicAdd(&gcnt[curg], cnt);
}

// Zin[g] = ((gfeat[g]/cnt) @ W_post + b_post) @ W_lin + b_lin ; zero if empty graph
__global__ void k_post1(const float* __restrict__ gfeat, const int* __restrict__ gcnt,
                        const float* __restrict__ W_post, const float* __restrict__ b_post,
                        const float* __restrict__ W_lin, const float* __restrict__ b_lin,
                        float* __restrict__ Zin) {
    int g = blockIdx.x, j = threadIdx.x;  // 128
    __shared__ float feat[832];
    __shared__ float z1[128];
    int cg = gcnt[g];
    float r = 1.f / ((cg > 0) ? (float)cg : 1.f);
    for (int i = j; i < 832; i += 128) feat[i] = gfeat[(size_t)g * 832 + i] * r;
    __syncthreads();
    float acc = b_post[j];
    for (int k = 0; k < 832; k++) acc += feat[k] * W_post[k * 128 + j];
    z1[j] = acc;
    __syncthreads();
    float a2 = b_lin[j];
    for (int k = 0; k < 128; k++) a2 += z1[k] * W_lin[k * 128 + j];
    if (cg == 0) a2 = 0.f;
    Zin[g * 128 + j] = a2;
}

// column-parallel MLP layer: block j computes output column j of
//   out = relu( BN(in' @ W + bias; gamma,beta) [+ res] ), in' = relu(BN(in)) if g_in
__global__ void k_mlpcol(const float* __restrict__ in, const float* __restrict__ W,
                         const float* __restrict__ bias,
                         const float* __restrict__ gamma, const float* __restrict__ beta,
                         const float* __restrict__ res,
                         const float* __restrict__ g_in, const float* __restrict__ be_in,
                         float* __restrict__ outp) {
    __shared__ float A[64 * 129];
    __shared__ float part[4 * 64];
    int t = threadIdx.x;  // 256
    int j = blockIdx.x;   // 128

    for (int i = t; i < 8192; i += 256) A[(i >> 7) * 129 + (i & 127)] = in[i];
    __syncthreads();

    if (g_in) {
        if (t < 128) {
            int c = t;
            float mu = 0.f;
            for (int r = 0; r < 64; r++) mu += A[r * 129 + c];
            mu *= (1.f / 64.f);
            float var = 0.f;
            for (int r = 0; r < 64; r++) { float d = A[r * 129 + c] - mu; var += d * d; }
            var *= (1.f / 64.f);
            float sc = rsqrtf(var + 1e-5f) * g_in[c], sh = be_in[c];
            for (int r = 0; r < 64; r++) {
                float v = (A[r * 129 + c] - mu) * sc + sh;
                A[r * 129 + c] = v > 0.f ? v : 0.f;
            }
        }
        __syncthreads();
    }

    int r = t & 63, q = t >> 6;
    float acc = 0.f;
    int k0 = q * 32;
    #pragma unroll
    for (int k = 0; k < 32; k++) acc += A[r * 129 + k0 + k] * W[(k0 + k) * 128 + j];
    part[q * 64 + r] = acc;
    __syncthreads();

    if (t < 64) {
        float v = part[t] + part[64 + t] + part[128 + t] + part[192 + t] + bias[j];
        float mu = wave_sum(v) * (1.f / 64.f);
        float d = v - mu;
        float var = wave_sum(d * d) * (1.f / 64.f);
        float o = d * rsqrtf(var + 1e-5f) * gamma[j] + beta[j];
        if (res) o += res[t * 128 + j];
        outp[t * 128 + j] = o > 0.f ? o : 0.f;
    }
}

__global__ void k_out(const float* __restrict__ z4, const float* __restrict__ W_out,
                      const float* b_out, float* __restrict__ out) {
    int g = threadIdx.x;  // 64
    float acc = b_out[0];
    for (int j = 0; j < 128; j++) acc += z4[g * 128 + j] * W_out[j];
    out[g] = acc;
}

extern "C" void kernel_launch(void* const* d_in, const int* in_sizes, int n_in,
                              void* d_out, int out_size, void* d_ws, size_t ws_size,
                              hipStream_t stream) {
    const float* x      = (const float*)d_in[0];
    const int*   ei     = (const int*)d_in[1];
    const float* ea     = (const float*)d_in[2];
    const int*   batch  = (const int*)d_in[3];
    const float* W_edge = (const float*)d_in[4];
    const float* b_edge = (const float*)d_in[5];
    const float* W_pre  = (const float*)d_in[6];
    const float* b_pre  = (const float*)d_in[7];
    const float* W_post = (const float*)d_in[8];
    const float* b_post = (const float*)d_in[9];
    const float* W_lin  = (const float*)d_in[10];
    const float* b_lin  = (const float*)d_in[11];
    const float* g1     = (const float*)d_in[12];
    const float* be1    = (const float*)d_in[13];
    const float* W2     = (const float*)d_in[14];
    const float* b2     = (const float*)d_in[15];
    const float* g2     = (const float*)d_in[16];
    const float* be2    = (const float*)d_in[17];
    const float* Wr1    = (const float*)d_in[18];
    const float* br1    = (const float*)d_in[19];
    const float* gr1    = (const float*)d_in[20];
    const float* ber1   = (const float*)d_in[21];
    const float* Wr2    = (const float*)d_in[22];
    const float* br2    = (const float*)d_in[23];
    const float* gr2    = (const float*)d_in[24];
    const float* ber2   = (const float*)d_in[25];
    const float* W_out  = (const float*)d_in[26];
    const float* b_out  = (const float*)d_in[27];
    float* out = (float*)d_out;

    const int N = in_sizes[0] / F;      // 50000  (must be <= 65536 for record packing)
    const int E = in_sizes[1] / 2;      // 800000
    const int G = out_size;             // 64
    const int NB = (N + BNODES - 1) >> BSH;  // 1563 buckets

    char* p = (char*)d_ws;
    auto alloc = [&](size_t nbytes) { void* r = p; p += (nbytes + 255) & ~(size_t)255; return r; };
    bf16*  AB     = (bf16*)alloc((size_t)N * 128 * sizeof(bf16));
    bf16*  agg    = (bf16*)alloc((size_t)N * 256 * sizeof(bf16));
    float* ampv   = (float*)alloc((size_t)N * sizeof(float));
    int*   gcur   = (int*)alloc((size_t)NB * sizeof(int));
    int2*  gout   = (int2*)alloc((size_t)NB * BCAP * sizeof(int2));
    float* uc     = (float*)alloc(128 * sizeof(float));
    float* gfeat  = (float*)alloc((size_t)G * 832 * sizeof(float));
    int*   gcnt   = (int*)alloc((size_t)G * sizeof(int));
    float* Zin    = (float*)alloc(64 * 128 * sizeof(float));
    float* z2b    = (float*)alloc(64 * 128 * sizeof(float));
    float* z3b    = (float*)alloc(64 * 128 * sizeof(float));
    float* z4b    = (float*)alloc(64 * 128 * sizeof(float));

    const int GF = G * 832;
    int initb = (GF + 255) / 256;
    if ((NB + 255) / 256 > initb) initb = (NB + 255) / 256;
    const int GRB = 1024;
    const int GRCH = (N + GRB - 1) / GRB;
    const int ABB = ((N + 15) / 16 + 3) / 4;
    const int NBT = (E + BTILE - 1) / BTILE;

    k_init<<<initb + 1, 256, 0, stream>>>(gcur, gfeat, gcnt, NB, GF, G,
                                          W_edge, b_edge, W_pre, b_pre, uc);
    k_ab_mfma<<<ABB, 256, 0, stream>>>(x, W_pre, AB, N);
    k_bucket<<<NBT, 1024, 0, stream>>>(ei, ea, gcur, gout, E, NB);
    k_edge<<<NB, 512, 0, stream>>>(AB, gout, gcur, uc, agg, ampv, N);
    k_greduce2<<<GRB, 256, 0, stream>>>(x, agg, ampv, batch, gfeat, gcnt, N, GRCH);
    k_post1<<<G, 128, 0, stream>>>(gfeat, gcnt, W_post, b_post, W_lin, b_lin, Zin);
    k_mlpcol<<<HG, 256, 0, stream>>>(Zin, W2, b2, g2, be2, nullptr, g1, be1, z2b);
    k_mlpcol<<<HL, 256, 0, stream>>>(z2b, Wr1, br1, gr1, ber1, nullptr, nullptr, nullptr, z3b);
    k_mlpcol<<<HL, 256, 0, stream>>>(z3b, Wr2, br2, gr2, ber2, z2b, nullptr, nullptr, z4b);
    k_out<<<1, 64, 0, stream>>>(z4b, W_out, b_out, out);
}